// Round 7
// baseline (335.435 us; speedup 1.0000x reference)
//
#include <hip/hip_runtime.h>
#include <cstdint>
#include <cstddef>

namespace {

constexpr int kB    = 64;
constexpr int kN    = 1024;
constexpr int kE    = 655360;
constexpr int kEper = kE / kB;     // 10240
constexpr int kH    = 128;
constexpr int kK1   = 820;
constexpr int kK2   = 656;
constexpr int kM1   = kB * kN;     // 65536
constexpr int kM2   = kB * kK1;    // 52480
constexpr int kM3   = kB * kK2;    // 41984
constexpr int kRChunks = 16;       // readout row-chunks per graph

typedef __attribute__((ext_vector_type(8))) short bf16x8;
typedef __attribute__((ext_vector_type(4))) float f32x4;

__device__ inline ushort f2bf(float f) {            // fp32 -> bf16 RNE bits
  uint u = __float_as_uint(f);
  return (ushort)((u + 0x7fffu + ((u >> 16) & 1u)) >> 16);
}
__device__ inline float bf2f(ushort s) { return __uint_as_float(((uint)s) << 16); }

// packed hi/lo split of 4 floats via v_cvt_pk_bf16_f32 (verified correct in R6:
// absmax stayed 0). 2 uints out per array = one 8-B ushort4 LDS write.
__device__ inline void cvt4(const float* f, uint* hh, uint* ll) {
#pragma unroll
  for (int i = 0; i < 2; ++i) {
    uint h;
    asm("v_cvt_pk_bf16_f32 %0, %1, %2" : "=v"(h) : "v"(f[2 * i]), "v"(f[2 * i + 1]));
    const float r0 = __uint_as_float(h << 16);
    const float r1 = __uint_as_float(h & 0xFFFF0000u);
    const float d0 = f[2 * i] - r0;
    const float d1 = f[2 * i + 1] - r1;
    uint l;
    asm("v_cvt_pk_bf16_f32 %0, %1, %2" : "=v"(l) : "v"(d0), "v"(d1));
    hh[i] = h; ll[i] = l;
  }
}

// inclusive block scan over 1024 threads: wave shfl-scan + 16-wavesum scan.
__device__ inline int block_scan_1024(int v, int* wsum /* LDS int[16] */) {
  const int lane = threadIdx.x & 63;
  const int w    = threadIdx.x >> 6;
#pragma unroll
  for (int off = 1; off < 64; off <<= 1) {
    const int n = __shfl_up(v, off);
    if (lane >= off) v += n;
  }
  if (lane == 63) wsum[w] = v;
  __syncthreads();
  if (w == 0) {
    int s = (lane < 16) ? wsum[lane] : 0;
#pragma unroll
    for (int off = 1; off < 16; off <<= 1) {
      const int n = __shfl_up(s, off);
      if (lane >= off) s += n;
    }
    if (lane < 16) wsum[lane] = s;
  }
  __syncthreads();
  if (w > 0) v += wsum[w - 1];
  return v;
}

// ===== fused CSR build + weight prep: one launch, 129 blocks =====
// blocks 0..63: per-graph LDS counting-sort CSR (ent = graph-local src ids).
// blocks 64..127: W^T hi/lo split (4 old 256-thr jobs per block, barrier-free).
// block 128: pw normalize, barrier-free (redundant 128-sum per thread).
__global__ __launch_bounds__(1024)
void build_prep(const int* __restrict__ src, const int* __restrict__ dst,
                int* __restrict__ coff, int* __restrict__ ccur,
                int* __restrict__ ent,
                const float* __restrict__ Wl1, const float* __restrict__ Wr1,
                const float* __restrict__ Wl2, const float* __restrict__ Wr2,
                const float* __restrict__ pw1, const float* __restrict__ pw2,
                ushort* __restrict__ W1h, ushort* __restrict__ W1l,
                ushort* __restrict__ W2h, ushort* __restrict__ W2l,
                float* __restrict__ pwn1, float* __restrict__ pwn2) {
  const int b   = blockIdx.x;
  const int tid = threadIdx.x;
  if (b >= 128) {                                    // pw normalize
    if (tid >= 256) return;
    const float* pw = (tid < 128) ? pw1 : pw2;
    float* o        = (tid < 128) ? pwn1 : pwn2;
    const int j = tid & 127;
    float sum = 0.0f;
    for (int k = 0; k < 128; ++k) { const float v = pw[k]; sum += v * v; }
    o[j] = pw[j] / sqrtf(sum);
    return;
  }
  if (b >= 64) {                                     // weight split
    const int ob  = (b - 64) * 4 + (tid >> 8);       // old prep block 0..255
    const bool l2 = ob >= 128;
    const int idx = (ob & 127) * 256 + (tid & 255);  // 0..32767
    const int n = idx >> 8, k = idx & 255;
    const float* Wl = l2 ? Wl2 : Wl1;
    const float* Wr = l2 ? Wr2 : Wr1;
    const float w = (k < 128) ? Wl[k * kH + n] : Wr[(k - 128) * kH + n];
    const ushort h = f2bf(w);
    (l2 ? W2h : W1h)[n * 256 + k] = h;
    (l2 ? W2l : W1l)[n * 256 + k] = f2bf(w - bf2f(h));
    return;
  }
  // ---- CSR build for graph b ----
  __shared__ int cnt[1024];
  __shared__ int wsum[16];
  const int g = b;
  const int ebase = g * kEper;
  cnt[tid] = 0;
  __syncthreads();
  for (int e = tid; e < kEper; e += 1024)
    atomicAdd(&cnt[dst[ebase + e] & (kN - 1)], 1);
  __syncthreads();
  const int dg   = cnt[tid];
  const int incl = block_scan_1024(dg, wsum);        // internal barriers
  const int start = ebase + incl - dg;               // exclusive scan
  coff[g * kN + tid] = start;
  ccur[g * kN + tid] = start + dg;                   // end offset
  __syncthreads();
  cnt[tid] = start;                                  // repurpose as cursor
  __syncthreads();
  for (int e = tid; e < kEper; e += 1024) {
    const int d   = dst[ebase + e] & (kN - 1);
    const int pos = atomicAdd(&cnt[d], 1);
    ent[pos] = src[ebase + e] & (kN - 1);
  }
}

// ================= LDS-staged gather-mean (v2) =================
// block = (graph, 16-col chunk); 64 KB feature slab in LDS; 4-lane group per
// node, one ds_read_b128 slot per edge (1024 B payload/wave-instr), edge ids
// hw-broadcast (same addr per 4 lanes), prefetched one body ahead.
__global__ __launch_bounds__(1024, 8)
void gather1_lds(const float* __restrict__ feat, const int* __restrict__ ent,
                 const int* __restrict__ off, const int* __restrict__ cursor,
                 float* __restrict__ aggout) {
  __shared__ float cache[1024 * 16];                 // 64 KB, stride 16 floats
  const int xcd   = blockIdx.x & 7;
  const int local = blockIdx.x >> 3;
  const int graph = xcd * 8 + (local >> 3);
  const int chunk = local & 7;
  const int tid   = threadIdx.x;
  const int gbase = graph << 10;

  // ---- stage: 1024 rows x 16 cols (64-B segments, 4 lanes/row) ----
#pragma unroll
  for (int ps = 0; ps < 4; ++ps) {
    const int row = ps * 256 + (tid >> 2);
    const int q   = (tid & 3) * 4;
    const float4 v = *(const float4*)(feat + (size_t)(gbase + row) * kH + chunk * 16 + q);
    *(float4*)&cache[row * 16 + q] = v;
  }
  __syncthreads();

  const int grp = tid >> 2;            // group id 0..255 = node within iter
  const int q4  = (tid & 3) * 4;       // this lane's 4 cols inside the chunk

  for (int it = 0; it < 4; ++it) {
    const int lnode = it * 256 + grp;
    const int node  = gbase + lnode;
    const int o0 = off[node];
    const int o1 = cursor[node];
    const int deg = o1 - o0;
    float4 acc = make_float4(0.f, 0.f, 0.f, 0.f);
    int pf[4];
#pragma unroll
    for (int i = 0; i < 4; ++i) pf[i] = (o0 + i < o1) ? ent[o0 + i] : 0;
    for (int eb = 0; eb < deg; eb += 4) {
      int nx[4];
#pragma unroll
      for (int i = 0; i < 4; ++i) {
        const int idx = o0 + eb + 4 + i;
        nx[i] = (idx < o1) ? ent[idx] : 0;
      }
#pragma unroll
      for (int i = 0; i < 4; ++i) {
        const float m = (eb + i < deg) ? 1.0f : 0.0f;   // mask tail (row 0 reads broadcast, free)
        const float4 v = *(const float4*)&cache[pf[i] * 16 + q4];
        acc.x = fmaf(v.x, m, acc.x);
        acc.y = fmaf(v.y, m, acc.y);
        acc.z = fmaf(v.z, m, acc.z);
        acc.w = fmaf(v.w, m, acc.w);
      }
#pragma unroll
      for (int i = 0; i < 4; ++i) pf[i] = nx[i];
    }
    const float r = 1.0f / fmaxf((float)deg, 1.0f);
    const f32x4 res = {acc.x * r, acc.y * r, acc.z * r, acc.w * r};
    __builtin_nontemporal_store(res, (f32x4*)(aggout + (size_t)node * kH + chunk * 16 + q4));
  }
}

// layer-2 variant (v3): raw ent (4 B/edge) + per-graph gated-score table gsg
// staged in LDS (4 KB): gs[l] = keep ? sc+2 : 0. Per edge: one ds_read_b128
// (features) + one ds_read_b32 (gate). cnt counts kept edges only.
__global__ __launch_bounds__(1024, 8)
void gather2_lds(const float* __restrict__ feat, const int* __restrict__ ent,
                 const int* __restrict__ off, const int* __restrict__ cursor,
                 const int* __restrict__ perm, const float* __restrict__ gsg,
                 float* __restrict__ aggout) {
  __shared__ float cache[1024 * 16];                 // 64 KB
  __shared__ float gs[1024];                         // 4 KB gated scores
  const int xcd   = blockIdx.x & 7;
  const int local = blockIdx.x >> 3;
  const int graph = xcd * 8 + (local >> 3);
  const int chunk = local & 7;
  const int tid   = threadIdx.x;
  const int gbase = graph << 10;

#pragma unroll
  for (int ps = 0; ps < 4; ++ps) {
    const int row = ps * 256 + (tid >> 2);
    const int q   = (tid & 3) * 4;
    const float4 v = *(const float4*)(feat + (size_t)(gbase + row) * kH + chunk * 16 + q);
    *(float4*)&cache[row * 16 + q] = v;
  }
  gs[tid] = gsg[gbase + tid];
  __syncthreads();

  const int grp = tid >> 2;
  const int q4  = (tid & 3) * 4;

  for (int it = 0; it < 4; ++it) {
    const int lnode = it * 256 + grp;                // valid < kK1 (820)
    int o0 = 0, o1 = 0;
    if (lnode < kK1) {
      const int orig = perm[graph * kK1 + lnode];
      o0 = off[orig];
      o1 = cursor[orig];
    }
    const int deg = o1 - o0;
    float4 acc = make_float4(0.f, 0.f, 0.f, 0.f);
    int cnt = 0;
    int pf[4];
#pragma unroll
    for (int i = 0; i < 4; ++i) pf[i] = (o0 + i < o1) ? ent[o0 + i] : 0;
    for (int eb = 0; eb < deg; eb += 4) {
      int nx[4];
#pragma unroll
      for (int i = 0; i < 4; ++i) {
        const int idx = o0 + eb + 4 + i;
        nx[i] = (idx < o1) ? ent[idx] : 0;
      }
#pragma unroll
      for (int i = 0; i < 4; ++i) {
        const float raw  = gs[pf[i]];
        const bool  kept = (raw > 0.5f) && (eb + i < deg);
        const float s    = kept ? raw - 2.0f : 0.0f;
        cnt += kept ? 1 : 0;
        const float4 v = *(const float4*)&cache[pf[i] * 16 + q4];
        acc.x = fmaf(v.x, s, acc.x);
        acc.y = fmaf(v.y, s, acc.y);
        acc.z = fmaf(v.z, s, acc.z);
        acc.w = fmaf(v.w, s, acc.w);
      }
#pragma unroll
      for (int i = 0; i < 4; ++i) pf[i] = nx[i];
    }
    const float r = 1.0f / fmaxf((float)cnt, 1.0f);
    const f32x4 res = {acc.x * r, acc.y * r, acc.z * r, acc.w * r};
    if (lnode < kK1)
      __builtin_nontemporal_store(res,
          (f32x4*)(aggout + (size_t)(graph * kK1 + lnode) * kH + chunk * 16 + q4));
  }
}

// ============ split-bf16 MFMA SAGE GEMM + fused score (v3, R17) ============
// R16 post-mortem: W-direct-from-global = 512B-strided 16B loads feeding MFMA
// (latency chain) AND grid gave only 4 blocks/CU = 16 waves = 50% occ cap ->
// 45 us, everything idle. v3: W staging back in LDS (R5's proven coalesced
// path), cvt_pk A-conversion kept, tile shrunk 64x128 -> 32x128 so LDS = 20 KB
// exactly -> 8 blocks/CU = 32 waves (100% cap, enforced by launch_bounds).
// sdot overlaid on aH (dead after the k-loop's final barrier).
__global__ __launch_bounds__(256, 8)
void sage_gemm_mfma(const float* __restrict__ meanb, const float* __restrict__ xsrc,
                    const int* __restrict__ perm, const float* __restrict__ gsc,
                    const ushort* __restrict__ WTh, const ushort* __restrict__ WTl,
                    const float* __restrict__ bias, const float* __restrict__ pwn,
                    float* __restrict__ outp, float* __restrict__ scr) {
  __shared__ __align__(16) ushort aH[32][32];    // [row][k]; reused as sdot after k-loop
  __shared__ __align__(16) ushort aL[32][32];
  __shared__ __align__(16) ushort wHs[128][32];  // [n][k] (= W^T)
  __shared__ __align__(16) ushort wLs[128][32];
  const int tid  = threadIdx.x;
  const int wid  = tid >> 6;
  const int lane = tid & 63;
  const int quad = lane >> 4;
  const int l16  = lane & 15;
  const int rowbase = blockIdx.x * 32;
  const int wr = (wid >> 1) * 16;                // wave row offset (0/16)
  const int wc = (wid & 1) * 64;                 // wave col offset (0/64)

  // A staging: each thread owns (row = tid>>3, 4 consecutive k)
  const int arow = tid >> 3;                     // 0..31
  const int k4   = (tid & 7) * 4;                // 0..28
  const int grow = rowbase + arow;
  int prow = grow; float pscale = 1.0f;
  if (perm) { prow = perm[grow]; pscale = gsc[grow]; }
  const float* mrow = meanb + (size_t)grow * kH;
  const float* xrow = xsrc + (size_t)prow * kH;

  f32x4 acc[4];
#pragma unroll
  for (int b = 0; b < 4; ++b) acc[b] = (f32x4){0.f, 0.f, 0.f, 0.f};

  for (int s = 0; s < 8; ++s) {                  // 8 k-steps of 32 over K=256
    const bool ismean = s < 4;
    const float* sp = ismean ? mrow : xrow;
    const float scl = ismean ? 1.0f : pscale;
    const int kloc  = (ismean ? s : s - 4) * 32;
    const int kbase = s * 32;
    // ---- stage A (fp32 -> bf16 hi/lo, packed cvt_pk) ----
    const float4 va = *(const float4*)(sp + kloc + k4);
    float f[4] = {va.x * scl, va.y * scl, va.z * scl, va.w * scl};
    uint hh[2], ll[2];
    cvt4(f, hh, ll);
    // ---- stage W^T hi/lo: 128 n x 32 k (coalesced 8B loads, L2-resident) ----
    ushort4 wh[4], wl[4];
#pragma unroll
    for (int i = 0; i < 4; ++i) {
      const int p  = tid + i * 256;
      const int n  = p >> 3;
      const int wk = (p & 7) * 4;
      wh[i] = *(const ushort4*)(WTh + n * 256 + kbase + wk);
      wl[i] = *(const ushort4*)(WTl + n * 256 + kbase + wk);
    }
    *(uint2*)&aH[arow][k4] = make_uint2(hh[0], hh[1]);
    *(uint2*)&aL[arow][k4] = make_uint2(ll[0], ll[1]);
#pragma unroll
    for (int i = 0; i < 4; ++i) {
      const int p  = tid + i * 256;
      const int n  = p >> 3;
      const int wk = (p & 7) * 4;
      *(ushort4*)&wHs[n][wk] = wh[i];
      *(ushort4*)&wLs[n][wk] = wl[i];
    }
    __syncthreads();
    // ---- fragments + MFMA ----
    const bf16x8 afh = *(const bf16x8*)&aH[wr + l16][quad * 8];
    const bf16x8 afl = *(const bf16x8*)&aL[wr + l16][quad * 8];
#pragma unroll
    for (int ct = 0; ct < 4; ++ct) {
      const bf16x8 bh = *(const bf16x8*)&wHs[wc + ct * 16 + l16][quad * 8];
      const bf16x8 bl = *(const bf16x8*)&wLs[wc + ct * 16 + l16][quad * 8];
      acc[ct] = __builtin_amdgcn_mfma_f32_16x16x32_bf16(afh, bh, acc[ct], 0, 0, 0);
      acc[ct] = __builtin_amdgcn_mfma_f32_16x16x32_bf16(afh, bl, acc[ct], 0, 0, 0);
      acc[ct] = __builtin_amdgcn_mfma_f32_16x16x32_bf16(afl, bh, acc[ct], 0, 0, 0);
    }
    __syncthreads();
  }
  // ---- epilogue: bias + relu + store + fused score ----
  float* sdot = (float*)aH;                      // overlay; all aH reads done
  float bv[4], pwv[4];
#pragma unroll
  for (int ct = 0; ct < 4; ++ct) {
    const int col = wc + ct * 16 + l16;
    bv[ct]  = bias[col];
    pwv[ct] = pwn[col];
  }
  float dot[4] = {0.f, 0.f, 0.f, 0.f};
#pragma unroll
  for (int ct = 0; ct < 4; ++ct) {
    const int col = wc + ct * 16 + l16;
#pragma unroll
    for (int reg = 0; reg < 4; ++reg) {
      const int row = rowbase + wr + quad * 4 + reg;
      const float o = fmaxf(acc[ct][reg] + bv[ct], 0.0f);
      outp[(size_t)row * kH + col] = o;
      dot[reg] += o * pwv[ct];
    }
  }
#pragma unroll
  for (int reg = 0; reg < 4; ++reg) {
    float d = dot[reg];
    d += __shfl_xor(d, 1);
    d += __shfl_xor(d, 2);
    d += __shfl_xor(d, 4);
    d += __shfl_xor(d, 8);
    if (l16 == 0) sdot[(wr + quad * 4 + reg) * 2 + (wc >> 6)] = d;
  }
  __syncthreads();
  if (tid < 32) scr[rowbase + tid] = tanhf(sdot[tid * 2] + sdot[tid * 2 + 1]);
}

// ================= fused top-K rank + compaction (radix select) =========
// 4-pass byte radix-select on order-preserving uint keys. Histogram from
// registers; bin suffix-scan inside wave 0 only. Yields threshold key T and
// rem = #(==T) to keep (lowest-index-first). One packed block scan of
// (gt<<11)|eq gives keep AND compaction position.
__global__ __launch_bounds__(1024)
void rank_compact(const float* __restrict__ scr, int n_per, int K,
                  int* __restrict__ perm, float* __restrict__ gsc,
                  float* __restrict__ gsg) {
  __shared__ int hist[256];
  __shared__ int wsum[16];
  __shared__ uint bT;
  __shared__ int bRem;
  const int g = blockIdx.x, tid = threadIdx.x;
  const float sc = (tid < n_per) ? scr[g * n_per + tid] : -3e30f;  // pad never wins
  const uint bits = __float_as_uint(sc);
  const uint key = (bits & 0x80000000u) ? ~bits : (bits | 0x80000000u);

  uint prefix = 0;
  int rem = K;
#pragma unroll
  for (int shift = 24; shift >= 0; shift -= 8) {
    if (tid < 256) hist[tid] = 0;
    __syncthreads();
    const uint mask = (shift == 24) ? 0u : (0xFFFFFFFFu << (shift + 8));
    if ((key & mask) == prefix)
      atomicAdd(&hist[(key >> shift) & 255], 1);
    __syncthreads();
    if (tid < 64) {
      const int h0 = hist[4 * tid + 0], h1 = hist[4 * tid + 1];
      const int h2 = hist[4 * tid + 2], h3 = hist[4 * tid + 3];
      const int loc = h0 + h1 + h2 + h3;
      int suf = loc;                       // inclusive suffix sum over lanes
#pragma unroll
      for (int d = 1; d < 64; d <<= 1) {
        const int o = __shfl_down(suf, d);
        if (tid + d < 64) suf += o;
      }
      const int above = suf - loc;         // strictly-higher lanes
      int hs[5];
      hs[4] = above;
      hs[3] = above + h3;
      hs[2] = hs[3] + h2;
      hs[1] = hs[2] + h1;
      hs[0] = hs[1] + h0;
#pragma unroll
      for (int q = 0; q < 4; ++q) {
        if (hs[q] >= rem && hs[q + 1] < rem) {   // unique crossing bin
          bT   = prefix | ((uint)(4 * tid + q) << shift);
          bRem = rem - hs[q + 1];
        }
      }
    }
    __syncthreads();
    prefix = bT;
    rem    = bRem;
  }
  // prefix == key of K-th largest; rem == #(==T) to keep (by lowest index).
  const int gt = (key > prefix) ? 1 : 0;
  const int eq = (key == prefix) ? 1 : 0;
  const int incl = block_scan_1024((gt << 11) | eq, wsum);   // internal barriers
  const int excl = incl - ((gt << 11) | eq);
  const int gt_excl = excl >> 11;
  const int eq_excl = excl & 2047;
  const int keep = (tid < n_per) && (gt || (eq && eq_excl < rem));
  if (keep) {
    const int pos = gt_excl + min(eq_excl, rem);
    perm[g * K + pos] = g * n_per + tid;
    gsc[g * K + pos]  = sc;
  }
  if (gsg) gsg[g * kN + tid] = keep ? sc + 2.0f : 0.0f;
}

// ---- readout stage 1: per-(graph, row-chunk) partial mean/max over gated rows ----
__global__ __launch_bounds__(256)
void readout_part(const float* __restrict__ h, const int* __restrict__ perm,
                  const float* __restrict__ gsc, int K,
                  float* __restrict__ psum, float* __restrict__ pmax) {
  const int g     = blockIdx.x >> 4;
  const int chunk = blockIdx.x & (kRChunks - 1);
  const int j     = threadIdx.x & 127;
  const int part  = threadIdx.x >> 7;            // 2 parts
  const int rows  = (K + kRChunks - 1) / kRChunks;
  const int r0 = chunk * rows;
  const int r1 = min(r0 + rows, K);
  float sum = 0.0f, mx = -1e30f;
  for (int r = r0 + part; r < r1; r += 2) {
    const int   row = perm[g * K + r];
    const float sc  = gsc[g * K + r];
    const float v   = h[(size_t)row * kH + j] * sc;
    sum += v;
    mx = fmaxf(mx, v);
  }
  __shared__ float ss[2][128], sm[2][128];
  ss[part][j] = sum;
  sm[part][j] = mx;
  __syncthreads();
  if (part == 0) {
    sum += ss[1][j];
    mx = fmaxf(mx, sm[1][j]);
    psum[(size_t)blockIdx.x * 128 + j] = sum;
    pmax[(size_t)blockIdx.x * 128 + j] = mx;
  }
}

// ---- fused: combine readout chunks (both layers) + 2-layer MLP head ----
__global__ __launch_bounds__(128)
void final_mlp(const float* __restrict__ ps1, const float* __restrict__ pm1,
               const float* __restrict__ ps2, const float* __restrict__ pm2,
               const float* __restrict__ fW1, const float* __restrict__ fb1,
               const float* __restrict__ fW2, const float* __restrict__ fb2,
               float* __restrict__ out) {
  __shared__ float xx[256];
  __shared__ float z[128];
  const int g = blockIdx.x, tid = threadIdx.x;
  float s1 = 0.f, m1 = -1e30f, s2 = 0.f, m2 = -1e30f;
#pragma unroll
  for (int c = 0; c < kRChunks; ++c) {
    s1 += ps1[(size_t)(g * kRChunks + c) * 128 + tid];
    m1 = fmaxf(m1, pm1[(size_t)(g * kRChunks + c) * 128 + tid]);
    s2 += ps2[(size_t)(g * kRChunks + c) * 128 + tid];
    m2 = fmaxf(m2, pm2[(size_t)(g * kRChunks + c) * 128 + tid]);
  }
  xx[tid]       = s1 / (float)kK1 + s2 / (float)kK2;
  xx[tid + 128] = m1 + m2;
  __syncthreads();
  float a = fb1[tid];
  for (int k = 0; k < 256; ++k) a += xx[k] * fW1[k * 128 + tid];
  z[tid] = fmaxf(a, 0.0f);
  __syncthreads();
  if (tid < 10) {
    float o = fb2[tid];
    for (int k = 0; k < 128; ++k) o += z[k] * fW2[k * 10 + tid];
    out[g * 10 + tid] = o;
  }
}

}  // namespace

extern "C" void kernel_launch(void* const* d_in, const int* in_sizes, int n_in,
                              void* d_out, int out_size, void* d_ws, size_t ws_size,
                              hipStream_t stream) {
  const float* x   = (const float*)d_in[0];
  const int*   ei  = (const int*)d_in[1];
  const float* Wl1 = (const float*)d_in[3];
  const float* bl1 = (const float*)d_in[4];
  const float* Wr1 = (const float*)d_in[5];
  const float* Wl2 = (const float*)d_in[6];
  const float* bl2 = (const float*)d_in[7];
  const float* Wr2 = (const float*)d_in[8];
  const float* pw1 = (const float*)d_in[9];
  const float* pw2 = (const float*)d_in[10];
  const float* fW1 = (const float*)d_in[11];
  const float* fb1 = (const float*)d_in[12];
  const float* fW2 = (const float*)d_in[13];
  const float* fb2 = (const float*)d_in[14];
  const int* src = ei;
  const int* dst = ei + kE;
  (void)in_sizes; (void)n_in; (void)out_size; (void)ws_size;

  char* wsb = (char*)d_ws;
  size_t off_b = 0;
  auto alloc = [&](size_t bytes) {
    void* p = wsb + off_b;
    off_b += (bytes + 255) & ~(size_t)255;
    return p;
  };
  float* bufA = (float*)alloc((size_t)kM1 * kH * 4);  // mean1 -> mean2
  float* bufB = (float*)alloc((size_t)kM1 * kH * 4);  // h1
  float* bufC = (float*)alloc((size_t)kM2 * kH * 4);  // h2
  int*   coff = (int*)alloc((size_t)kM1 * 4);
  int*   ccur = (int*)alloc((size_t)kM1 * 4);
  int*   ent  = (int*)alloc((size_t)kE * 4);
  float* scr  = (float*)alloc((size_t)kM1 * 4);
  float* gsg  = (float*)alloc((size_t)kM1 * 4);
  int*   perm1= (int*)alloc((size_t)kM2 * 4);
  float* gsc1 = (float*)alloc((size_t)kM2 * 4);
  int*   perm2= (int*)alloc((size_t)kM3 * 4);
  float* gsc2 = (float*)alloc((size_t)kM3 * 4);
  float* psum1= (float*)alloc((size_t)kB * kRChunks * 128 * 4);
  float* pmax1= (float*)alloc((size_t)kB * kRChunks * 128 * 4);
  float* psum2= (float*)alloc((size_t)kB * kRChunks * 128 * 4);
  float* pmax2= (float*)alloc((size_t)kB * kRChunks * 128 * 4);
  ushort* wt1h = (ushort*)alloc((size_t)128 * 256 * 2);
  ushort* wt1l = (ushort*)alloc((size_t)128 * 256 * 2);
  ushort* wt2h = (ushort*)alloc((size_t)128 * 256 * 2);
  ushort* wt2l = (ushort*)alloc((size_t)128 * 256 * 2);
  float* pwn1 = (float*)alloc(128 * 4);
  float* pwn2 = (float*)alloc(128 * 4);

  // ---------------- fused CSR build + prep ----------------
  build_prep<<<129, 1024, 0, stream>>>(src, dst, coff, ccur, ent,
                                       Wl1, Wr1, Wl2, Wr2, pw1, pw2,
                                       wt1h, wt1l, wt2h, wt2l, pwn1, pwn2);

  // ---------------- layer 1 ----------------
  gather1_lds<<<kB * 8, 1024, 0, stream>>>(x, ent, coff, ccur, bufA);
  sage_gemm_mfma<<<kM1 / 32, 256, 0, stream>>>(bufA, x, nullptr, nullptr,
                                               wt1h, wt1l, bl1, pwn1, bufB, scr);
  rank_compact<<<kB, 1024, 0, stream>>>(scr, kN, kK1, perm1, gsc1, gsg);
  readout_part<<<kB * kRChunks, 256, 0, stream>>>(bufB, perm1, gsc1, kK1, psum1, pmax1);

  // ---------------- layer 2 (reuses layer-1 CSR; gate staged in gather2 LDS) ----
  gather2_lds<<<kB * 8, 1024, 0, stream>>>(bufB, ent, coff, ccur, perm1, gsg, bufA);
  sage_gemm_mfma<<<kM2 / 32, 256, 0, stream>>>(bufA, bufB, perm1, gsc1,
                                               wt2h, wt2l, bl2, pwn2, bufC, scr);
  rank_compact<<<kB, 1024, 0, stream>>>(scr, kK1, kK2, perm2, gsc2, nullptr);
  readout_part<<<kB * kRChunks, 256, 0, stream>>>(bufC, perm2, gsc2, kK2, psum2, pmax2);

  // ---------------- head ----------------
  final_mlp<<<kB, 128, 0, stream>>>(psum1, pmax1, psum2, pmax2,
                                    fW1, fb1, fW2, fb2, (float*)d_out);
}

// Round 8
// 295.314 us; speedup vs baseline: 1.1359x; 1.1359x over previous
//
#include <hip/hip_runtime.h>
#include <cstdint>
#include <cstddef>

namespace {

constexpr int kB    = 64;
constexpr int kN    = 1024;
constexpr int kE    = 655360;
constexpr int kEper = kE / kB;     // 10240
constexpr int kH    = 128;
constexpr int kK1   = 820;
constexpr int kK2   = 656;
constexpr int kM1   = kB * kN;     // 65536
constexpr int kM2   = kB * kK1;    // 52480
constexpr int kM3   = kB * kK2;    // 41984
constexpr int kRChunks = 16;       // readout row-chunks per graph

typedef __attribute__((ext_vector_type(8))) short bf16x8;
typedef __attribute__((ext_vector_type(4))) float f32x4;

__device__ inline ushort f2bf(float f) {            // fp32 -> bf16 RNE bits
  uint u = __float_as_uint(f);
  return (ushort)((u + 0x7fffu + ((u >> 16) & 1u)) >> 16);
}
__device__ inline float bf2f(ushort s) { return __uint_as_float(((uint)s) << 16); }

// packed hi/lo split of 8 floats via v_cvt_pk_bf16_f32 (verified: absmax 0 in
// R6/R7). Output uints are the 4 dwords of a bf16x8 fragment.
__device__ inline void cvt8(const float* f, uint* hh, uint* ll) {
#pragma unroll
  for (int i = 0; i < 4; ++i) {
    uint h;
    asm("v_cvt_pk_bf16_f32 %0, %1, %2" : "=v"(h) : "v"(f[2 * i]), "v"(f[2 * i + 1]));
    const float r0 = __uint_as_float(h << 16);
    const float r1 = __uint_as_float(h & 0xFFFF0000u);
    const float d0 = f[2 * i] - r0;
    const float d1 = f[2 * i + 1] - r1;
    uint l;
    asm("v_cvt_pk_bf16_f32 %0, %1, %2" : "=v"(l) : "v"(d0), "v"(d1));
    hh[i] = h; ll[i] = l;
  }
}

__device__ inline bf16x8 pack8(const uint* h) {
  union { uint u[4]; bf16x8 v; } t;
  t.u[0] = h[0]; t.u[1] = h[1]; t.u[2] = h[2]; t.u[3] = h[3];
  return t.v;
}

// inclusive block scan over 1024 threads: wave shfl-scan + 16-wavesum scan.
__device__ inline int block_scan_1024(int v, int* wsum /* LDS int[16] */) {
  const int lane = threadIdx.x & 63;
  const int w    = threadIdx.x >> 6;
#pragma unroll
  for (int off = 1; off < 64; off <<= 1) {
    const int n = __shfl_up(v, off);
    if (lane >= off) v += n;
  }
  if (lane == 63) wsum[w] = v;
  __syncthreads();
  if (w == 0) {
    int s = (lane < 16) ? wsum[lane] : 0;
#pragma unroll
    for (int off = 1; off < 16; off <<= 1) {
      const int n = __shfl_up(s, off);
      if (lane >= off) s += n;
    }
    if (lane < 16) wsum[lane] = s;
  }
  __syncthreads();
  if (w > 0) v += wsum[w - 1];
  return v;
}

// ===== fused CSR build + weight prep: one launch, 129 blocks =====
__global__ __launch_bounds__(1024)
void build_prep(const int* __restrict__ src, const int* __restrict__ dst,
                int* __restrict__ coff, int* __restrict__ ccur,
                int* __restrict__ ent,
                const float* __restrict__ Wl1, const float* __restrict__ Wr1,
                const float* __restrict__ Wl2, const float* __restrict__ Wr2,
                const float* __restrict__ pw1, const float* __restrict__ pw2,
                ushort* __restrict__ W1h, ushort* __restrict__ W1l,
                ushort* __restrict__ W2h, ushort* __restrict__ W2l,
                float* __restrict__ pwn1, float* __restrict__ pwn2) {
  const int b   = blockIdx.x;
  const int tid = threadIdx.x;
  if (b >= 128) {                                    // pw normalize
    if (tid >= 256) return;
    const float* pw = (tid < 128) ? pw1 : pw2;
    float* o        = (tid < 128) ? pwn1 : pwn2;
    const int j = tid & 127;
    float sum = 0.0f;
    for (int k = 0; k < 128; ++k) { const float v = pw[k]; sum += v * v; }
    o[j] = pw[j] / sqrtf(sum);
    return;
  }
  if (b >= 64) {                                     // weight split
    const int ob  = (b - 64) * 4 + (tid >> 8);       // old prep block 0..255
    const bool l2 = ob >= 128;
    const int idx = (ob & 127) * 256 + (tid & 255);  // 0..32767
    const int n = idx >> 8, k = idx & 255;
    const float* Wl = l2 ? Wl2 : Wl1;
    const float* Wr = l2 ? Wr2 : Wr1;
    const float w = (k < 128) ? Wl[k * kH + n] : Wr[(k - 128) * kH + n];
    const ushort h = f2bf(w);
    (l2 ? W2h : W1h)[n * 256 + k] = h;
    (l2 ? W2l : W1l)[n * 256 + k] = f2bf(w - bf2f(h));
    return;
  }
  // ---- CSR build for graph b ----
  __shared__ int cnt[1024];
  __shared__ int wsum[16];
  const int g = b;
  const int ebase = g * kEper;
  cnt[tid] = 0;
  __syncthreads();
  for (int e = tid; e < kEper; e += 1024)
    atomicAdd(&cnt[dst[ebase + e] & (kN - 1)], 1);
  __syncthreads();
  const int dg   = cnt[tid];
  const int incl = block_scan_1024(dg, wsum);        // internal barriers
  const int start = ebase + incl - dg;               // exclusive scan
  coff[g * kN + tid] = start;
  ccur[g * kN + tid] = start + dg;                   // end offset
  __syncthreads();
  cnt[tid] = start;                                  // repurpose as cursor
  __syncthreads();
  for (int e = tid; e < kEper; e += 1024) {
    const int d   = dst[ebase + e] & (kN - 1);
    const int pos = atomicAdd(&cnt[d], 1);
    ent[pos] = src[ebase + e] & (kN - 1);
  }
}

// ================= LDS-staged gather-mean (v2) =================
__global__ __launch_bounds__(1024, 8)
void gather1_lds(const float* __restrict__ feat, const int* __restrict__ ent,
                 const int* __restrict__ off, const int* __restrict__ cursor,
                 float* __restrict__ aggout) {
  __shared__ float cache[1024 * 16];                 // 64 KB, stride 16 floats
  const int xcd   = blockIdx.x & 7;
  const int local = blockIdx.x >> 3;
  const int graph = xcd * 8 + (local >> 3);
  const int chunk = local & 7;
  const int tid   = threadIdx.x;
  const int gbase = graph << 10;

#pragma unroll
  for (int ps = 0; ps < 4; ++ps) {
    const int row = ps * 256 + (tid >> 2);
    const int q   = (tid & 3) * 4;
    const float4 v = *(const float4*)(feat + (size_t)(gbase + row) * kH + chunk * 16 + q);
    *(float4*)&cache[row * 16 + q] = v;
  }
  __syncthreads();

  const int grp = tid >> 2;            // group id 0..255 = node within iter
  const int q4  = (tid & 3) * 4;       // this lane's 4 cols inside the chunk

  for (int it = 0; it < 4; ++it) {
    const int lnode = it * 256 + grp;
    const int node  = gbase + lnode;
    const int o0 = off[node];
    const int o1 = cursor[node];
    const int deg = o1 - o0;
    float4 acc = make_float4(0.f, 0.f, 0.f, 0.f);
    int pf[4];
#pragma unroll
    for (int i = 0; i < 4; ++i) pf[i] = (o0 + i < o1) ? ent[o0 + i] : 0;
    for (int eb = 0; eb < deg; eb += 4) {
      int nx[4];
#pragma unroll
      for (int i = 0; i < 4; ++i) {
        const int idx = o0 + eb + 4 + i;
        nx[i] = (idx < o1) ? ent[idx] : 0;
      }
#pragma unroll
      for (int i = 0; i < 4; ++i) {
        const float m = (eb + i < deg) ? 1.0f : 0.0f;   // mask tail
        const float4 v = *(const float4*)&cache[pf[i] * 16 + q4];
        acc.x = fmaf(v.x, m, acc.x);
        acc.y = fmaf(v.y, m, acc.y);
        acc.z = fmaf(v.z, m, acc.z);
        acc.w = fmaf(v.w, m, acc.w);
      }
#pragma unroll
      for (int i = 0; i < 4; ++i) pf[i] = nx[i];
    }
    const float r = 1.0f / fmaxf((float)deg, 1.0f);
    const f32x4 res = {acc.x * r, acc.y * r, acc.z * r, acc.w * r};
    __builtin_nontemporal_store(res, (f32x4*)(aggout + (size_t)node * kH + chunk * 16 + q4));
  }
}

// layer-2 variant (v3): raw ent + per-graph gated-score table gsg in LDS.
__global__ __launch_bounds__(1024, 8)
void gather2_lds(const float* __restrict__ feat, const int* __restrict__ ent,
                 const int* __restrict__ off, const int* __restrict__ cursor,
                 const int* __restrict__ perm, const float* __restrict__ gsg,
                 float* __restrict__ aggout) {
  __shared__ float cache[1024 * 16];                 // 64 KB
  __shared__ float gs[1024];                         // 4 KB gated scores
  const int xcd   = blockIdx.x & 7;
  const int local = blockIdx.x >> 3;
  const int graph = xcd * 8 + (local >> 3);
  const int chunk = local & 7;
  const int tid   = threadIdx.x;
  const int gbase = graph << 10;

#pragma unroll
  for (int ps = 0; ps < 4; ++ps) {
    const int row = ps * 256 + (tid >> 2);
    const int q   = (tid & 3) * 4;
    const float4 v = *(const float4*)(feat + (size_t)(gbase + row) * kH + chunk * 16 + q);
    *(float4*)&cache[row * 16 + q] = v;
  }
  gs[tid] = gsg[gbase + tid];
  __syncthreads();

  const int grp = tid >> 2;
  const int q4  = (tid & 3) * 4;

  for (int it = 0; it < 4; ++it) {
    const int lnode = it * 256 + grp;                // valid < kK1 (820)
    int o0 = 0, o1 = 0;
    if (lnode < kK1) {
      const int orig = perm[graph * kK1 + lnode];
      o0 = off[orig];
      o1 = cursor[orig];
    }
    const int deg = o1 - o0;
    float4 acc = make_float4(0.f, 0.f, 0.f, 0.f);
    int cnt = 0;
    int pf[4];
#pragma unroll
    for (int i = 0; i < 4; ++i) pf[i] = (o0 + i < o1) ? ent[o0 + i] : 0;
    for (int eb = 0; eb < deg; eb += 4) {
      int nx[4];
#pragma unroll
      for (int i = 0; i < 4; ++i) {
        const int idx = o0 + eb + 4 + i;
        nx[i] = (idx < o1) ? ent[idx] : 0;
      }
#pragma unroll
      for (int i = 0; i < 4; ++i) {
        const float raw  = gs[pf[i]];
        const bool  kept = (raw > 0.5f) && (eb + i < deg);
        const float s    = kept ? raw - 2.0f : 0.0f;
        cnt += kept ? 1 : 0;
        const float4 v = *(const float4*)&cache[pf[i] * 16 + q4];
        acc.x = fmaf(v.x, s, acc.x);
        acc.y = fmaf(v.y, s, acc.y);
        acc.z = fmaf(v.z, s, acc.z);
        acc.w = fmaf(v.w, s, acc.w);
      }
#pragma unroll
      for (int i = 0; i < 4; ++i) pf[i] = nx[i];
    }
    const float r = 1.0f / fmaxf((float)cnt, 1.0f);
    const f32x4 res = {acc.x * r, acc.y * r, acc.z * r, acc.w * r};
    if (lnode < kK1)
      __builtin_nontemporal_store(res,
          (f32x4*)(aggout + (size_t)(graph * kK1 + lnode) * kH + chunk * 16 + q4));
  }
}

// ========= streaming split-bf16 MFMA SAGE GEMM (v4, R18) =========
// R7 post-mortem: barrier-locked k-loop (2 barriers/k-step) + per-k-step W
// staging was the bottleneck, not occupancy (66% occ yet 7% MfmaUtil).
// v4: W (128 KB hi+lo) staged ONCE per block into LDS in PRECOMPUTED
// FRAGMENT ORDER -> every ds_read_b128 is a linear 1024B wave burst: zero
// bank conflicts, zero address VALU (compile-time offsets). A is loaded
// register-direct from global in fragment layout (lane=row l&15, k=quad*8;
// the 4 quads tile one 128B line per row -> dense). NO barriers in k-loop.
// 1024 thr = 16 waves (4 rowgrp x 4 colgrp); block = 256 rows x 128 cols;
// wave = 64 rows x 32 cols (rt=4, ct=2). LDS 132 KB -> 1 block/CU; grid =
// rows/256 blocks = 1/CU, waves fully independent.
__global__ __launch_bounds__(1024, 4)
void sage_gemm_mfma(const float* __restrict__ meanb, const float* __restrict__ xsrc,
                    const int* __restrict__ perm, const float* __restrict__ gsc,
                    const ushort* __restrict__ WTh, const ushort* __restrict__ WTl,
                    const float* __restrict__ bias, const float* __restrict__ pwn,
                    float* __restrict__ outp, float* __restrict__ scr) {
  __shared__ __align__(16) ushort wfH[32768];    // 64 KB: frag chunk (cf,s,lane)
  __shared__ __align__(16) ushort wfL[32768];    // 64 KB
  __shared__ float sdot[256][4];                 // per-row score partials per colgrp
  const int tid  = threadIdx.x;
  const int lane = tid & 63;
  const int wid  = tid >> 6;
  const int rg   = wid >> 2;                     // row group 0..3 (64 rows each)
  const int cg   = wid & 3;                      // col group 0..3 (32 cols each)
  const int quad = lane >> 4;
  const int l16  = lane & 15;
  const int rowbase = blockIdx.x * 256;

  // ---- stage W fragment tables once: chunk c=(cf*8+s)*64+l holds
  //      W^T[cf*16+(l&15)][s*32+(l>>4)*8 .. +7] ----
#pragma unroll
  for (int i = 0; i < 4; ++i) {
    const int c  = tid + i * 1024;
    const int l  = c & 63;
    const int s  = (c >> 6) & 7;
    const int cf = c >> 9;
    const int n  = cf * 16 + (l & 15);
    const int ks = s * 32 + (l >> 4) * 8;
    *(uint4*)&wfH[c * 8] = *(const uint4*)(WTh + n * 256 + ks);
    *(uint4*)&wfL[c * 8] = *(const uint4*)(WTl + n * 256 + ks);
  }

  // per-lane row info (hoisted; lane's fragment row = +l16)
  int grow[4], prow[4];
  float pscale[4];
#pragma unroll
  for (int rt = 0; rt < 4; ++rt) {
    grow[rt] = rowbase + rg * 64 + rt * 16 + l16;
    prow[rt] = grow[rt];
    pscale[rt] = 1.0f;
    if (perm) { prow[rt] = perm[grow[rt]]; pscale[rt] = gsc[grow[rt]]; }
  }
  __syncthreads();                               // W table ready; last barrier
                                                 // until epilogue

  const ushort* wHb = wfH + cg * 8192 + lane * 8;  // cg*2 colfrags * 8 s * 512
  const ushort* wLb = wfL + cg * 8192 + lane * 8;

  f32x4 acc[4][2];
#pragma unroll
  for (int rt = 0; rt < 4; ++rt)
#pragma unroll
    for (int ct = 0; ct < 2; ++ct) acc[rt][ct] = (f32x4){0.f, 0.f, 0.f, 0.f};

#pragma unroll
  for (int s = 0; s < 8; ++s) {                  // 8 k-steps of 32; barrier-free
    const bool ismean = s < 4;
    const int kf = (ismean ? s : s - 4) * 32 + quad * 8;
    bf16x8 ah[4], al[4];
#pragma unroll
    for (int rt = 0; rt < 4; ++rt) {
      const float* rp = ismean ? (meanb + (size_t)grow[rt] * kH)
                               : (xsrc + (size_t)prow[rt] * kH);
      const float4 v0 = *(const float4*)(rp + kf);
      const float4 v1 = *(const float4*)(rp + kf + 4);
      const float scl = ismean ? 1.0f : pscale[rt];
      float f[8] = {v0.x * scl, v0.y * scl, v0.z * scl, v0.w * scl,
                    v1.x * scl, v1.y * scl, v1.z * scl, v1.w * scl};
      uint hh[4], ll[4];
      cvt8(f, hh, ll);
      ah[rt] = pack8(hh);
      al[rt] = pack8(ll);
    }
#pragma unroll
    for (int ct = 0; ct < 2; ++ct) {
      const bf16x8 bh = *(const bf16x8*)(wHb + (ct * 8 + s) * 512);
      const bf16x8 bl = *(const bf16x8*)(wLb + (ct * 8 + s) * 512);
#pragma unroll
      for (int rt = 0; rt < 4; ++rt) {
        acc[rt][ct] = __builtin_amdgcn_mfma_f32_16x16x32_bf16(ah[rt], bh, acc[rt][ct], 0, 0, 0);
        acc[rt][ct] = __builtin_amdgcn_mfma_f32_16x16x32_bf16(ah[rt], bl, acc[rt][ct], 0, 0, 0);
        acc[rt][ct] = __builtin_amdgcn_mfma_f32_16x16x32_bf16(al[rt], bh, acc[rt][ct], 0, 0, 0);
      }
    }
  }

  // ---- epilogue: bias + relu + store + fused score ----
  const int colbase = cg * 32;
  float bv[2], pwv[2];
#pragma unroll
  for (int ct = 0; ct < 2; ++ct) {
    const int col = colbase + ct * 16 + l16;
    bv[ct]  = bias[col];
    pwv[ct] = pwn[col];
  }
  float dot[4][4];
#pragma unroll
  for (int rt = 0; rt < 4; ++rt)
#pragma unroll
    for (int reg = 0; reg < 4; ++reg) dot[rt][reg] = 0.0f;
#pragma unroll
  for (int ct = 0; ct < 2; ++ct) {
    const int col = colbase + ct * 16 + l16;
#pragma unroll
    for (int rt = 0; rt < 4; ++rt) {
#pragma unroll
      for (int reg = 0; reg < 4; ++reg) {
        const int row = rowbase + rg * 64 + rt * 16 + quad * 4 + reg;
        const float o = fmaxf(acc[rt][ct][reg] + bv[ct], 0.0f);
        outp[(size_t)row * kH + col] = o;
        dot[rt][reg] += o * pwv[ct];
      }
    }
  }
#pragma unroll
  for (int rt = 0; rt < 4; ++rt) {
#pragma unroll
    for (int reg = 0; reg < 4; ++reg) {
      float d = dot[rt][reg];
      d += __shfl_xor(d, 1);
      d += __shfl_xor(d, 2);
      d += __shfl_xor(d, 4);
      d += __shfl_xor(d, 8);
      if (l16 == 0) sdot[rg * 64 + rt * 16 + quad * 4 + reg][cg] = d;
    }
  }
  __syncthreads();
  if (tid < 256) {
    const float4 sd = *(const float4*)&sdot[tid][0];
    scr[rowbase + tid] = tanhf(sd.x + sd.y + sd.z + sd.w);
  }
}

// ================= fused top-K rank + compaction (radix select) =========
__global__ __launch_bounds__(1024)
void rank_compact(const float* __restrict__ scr, int n_per, int K,
                  int* __restrict__ perm, float* __restrict__ gsc,
                  float* __restrict__ gsg) {
  __shared__ int hist[256];
  __shared__ int wsum[16];
  __shared__ uint bT;
  __shared__ int bRem;
  const int g = blockIdx.x, tid = threadIdx.x;
  const float sc = (tid < n_per) ? scr[g * n_per + tid] : -3e30f;  // pad never wins
  const uint bits = __float_as_uint(sc);
  const uint key = (bits & 0x80000000u) ? ~bits : (bits | 0x80000000u);

  uint prefix = 0;
  int rem = K;
#pragma unroll
  for (int shift = 24; shift >= 0; shift -= 8) {
    if (tid < 256) hist[tid] = 0;
    __syncthreads();
    const uint mask = (shift == 24) ? 0u : (0xFFFFFFFFu << (shift + 8));
    if ((key & mask) == prefix)
      atomicAdd(&hist[(key >> shift) & 255], 1);
    __syncthreads();
    if (tid < 64) {
      const int h0 = hist[4 * tid + 0], h1 = hist[4 * tid + 1];
      const int h2 = hist[4 * tid + 2], h3 = hist[4 * tid + 3];
      const int loc = h0 + h1 + h2 + h3;
      int suf = loc;                       // inclusive suffix sum over lanes
#pragma unroll
      for (int d = 1; d < 64; d <<= 1) {
        const int o = __shfl_down(suf, d);
        if (tid + d < 64) suf += o;
      }
      const int above = suf - loc;         // strictly-higher lanes
      int hs[5];
      hs[4] = above;
      hs[3] = above + h3;
      hs[2] = hs[3] + h2;
      hs[1] = hs[2] + h1;
      hs[0] = hs[1] + h0;
#pragma unroll
      for (int q = 0; q < 4; ++q) {
        if (hs[q] >= rem && hs[q + 1] < rem) {   // unique crossing bin
          bT   = prefix | ((uint)(4 * tid + q) << shift);
          bRem = rem - hs[q + 1];
        }
      }
    }
    __syncthreads();
    prefix = bT;
    rem    = bRem;
  }
  const int gt = (key > prefix) ? 1 : 0;
  const int eq = (key == prefix) ? 1 : 0;
  const int incl = block_scan_1024((gt << 11) | eq, wsum);   // internal barriers
  const int excl = incl - ((gt << 11) | eq);
  const int gt_excl = excl >> 11;
  const int eq_excl = excl & 2047;
  const int keep = (tid < n_per) && (gt || (eq && eq_excl < rem));
  if (keep) {
    const int pos = gt_excl + min(eq_excl, rem);
    perm[g * K + pos] = g * n_per + tid;
    gsc[g * K + pos]  = sc;
  }
  if (gsg) gsg[g * kN + tid] = keep ? sc + 2.0f : 0.0f;
}

// ---- readout stage 1: per-(graph, row-chunk) partial mean/max over gated rows ----
__global__ __launch_bounds__(256)
void readout_part(const float* __restrict__ h, const int* __restrict__ perm,
                  const float* __restrict__ gsc, int K,
                  float* __restrict__ psum, float* __restrict__ pmax) {
  const int g     = blockIdx.x >> 4;
  const int chunk = blockIdx.x & (kRChunks - 1);
  const int j     = threadIdx.x & 127;
  const int part  = threadIdx.x >> 7;            // 2 parts
  const int rows  = (K + kRChunks - 1) / kRChunks;
  const int r0 = chunk * rows;
  const int r1 = min(r0 + rows, K);
  float sum = 0.0f, mx = -1e30f;
  for (int r = r0 + part; r < r1; r += 2) {
    const int   row = perm[g * K + r];
    const float sc  = gsc[g * K + r];
    const float v   = h[(size_t)row * kH + j] * sc;
    sum += v;
    mx = fmaxf(mx, v);
  }
  __shared__ float ss[2][128], sm[2][128];
  ss[part][j] = sum;
  sm[part][j] = mx;
  __syncthreads();
  if (part == 0) {
    sum += ss[1][j];
    mx = fmaxf(mx, sm[1][j]);
    psum[(size_t)blockIdx.x * 128 + j] = sum;
    pmax[(size_t)blockIdx.x * 128 + j] = mx;
  }
}

// ---- fused: combine readout chunks (both layers) + 2-layer MLP head ----
__global__ __launch_bounds__(128)
void final_mlp(const float* __restrict__ ps1, const float* __restrict__ pm1,
               const float* __restrict__ ps2, const float* __restrict__ pm2,
               const float* __restrict__ fW1, const float* __restrict__ fb1,
               const float* __restrict__ fW2, const float* __restrict__ fb2,
               float* __restrict__ out) {
  __shared__ float xx[256];
  __shared__ float z[128];
  const int g = blockIdx.x, tid = threadIdx.x;
  float s1 = 0.f, m1 = -1e30f, s2 = 0.f, m2 = -1e30f;
#pragma unroll
  for (int c = 0; c < kRChunks; ++c) {
    s1 += ps1[(size_t)(g * kRChunks + c) * 128 + tid];
    m1 = fmaxf(m1, pm1[(size_t)(g * kRChunks + c) * 128 + tid]);
    s2 += ps2[(size_t)(g * kRChunks + c) * 128 + tid];
    m2 = fmaxf(m2, pm2[(size_t)(g * kRChunks + c) * 128 + tid]);
  }
  xx[tid]       = s1 / (float)kK1 + s2 / (float)kK2;
  xx[tid + 128] = m1 + m2;
  __syncthreads();
  float a = fb1[tid];
  for (int k = 0; k < 256; ++k) a += xx[k] * fW1[k * 128 + tid];
  z[tid] = fmaxf(a, 0.0f);
  __syncthreads();
  if (tid < 10) {
    float o = fb2[tid];
    for (int k = 0; k < 128; ++k) o += z[k] * fW2[k * 10 + tid];
    out[g * 10 + tid] = o;
  }
}

}  // namespace

extern "C" void kernel_launch(void* const* d_in, const int* in_sizes, int n_in,
                              void* d_out, int out_size, void* d_ws, size_t ws_size,
                              hipStream_t stream) {
  const float* x   = (const float*)d_in[0];
  const int*   ei  = (const int*)d_in[1];
  const float* Wl1 = (const float*)d_in[3];
  const float* bl1 = (const float*)d_in[4];
  const float* Wr1 = (const float*)d_in[5];
  const float* Wl2 = (const float*)d_in[6];
  const float* bl2 = (const float*)d_in[7];
  const float* Wr2 = (const float*)d_in[8];
  const float* pw1 = (const float*)d_in[9];
  const float* pw2 = (const float*)d_in[10];
  const float* fW1 = (const float*)d_in[11];
  const float* fb1 = (const float*)d_in[12];
  const float* fW2 = (const float*)d_in[13];
  const float* fb2 = (const float*)d_in[14];
  const int* src = ei;
  const int* dst = ei + kE;
  (void)in_sizes; (void)n_in; (void)out_size; (void)ws_size;

  char* wsb = (char*)d_ws;
  size_t off_b = 0;
  auto alloc = [&](size_t bytes) {
    void* p = wsb + off_b;
    off_b += (bytes + 255) & ~(size_t)255;
    return p;
  };
  float* bufA = (float*)alloc((size_t)kM1 * kH * 4);  // mean1 -> mean2
  float* bufB = (float*)alloc((size_t)kM1 * kH * 4);  // h1
  float* bufC = (float*)alloc((size_t)kM2 * kH * 4);  // h2
  int*   coff = (int*)alloc((size_t)kM1 * 4);
  int*   ccur = (int*)alloc((size_t)kM1 * 4);
  int*   ent  = (int*)alloc((size_t)kE * 4);
  float* scr  = (float*)alloc((size_t)kM1 * 4);
  float* gsg  = (float*)alloc((size_t)kM1 * 4);
  int*   perm1= (int*)alloc((size_t)kM2 * 4);
  float* gsc1 = (float*)alloc((size_t)kM2 * 4);
  int*   perm2= (int*)alloc((size_t)kM3 * 4);
  float* gsc2 = (float*)alloc((size_t)kM3 * 4);
  float* psum1= (float*)alloc((size_t)kB * kRChunks * 128 * 4);
  float* pmax1= (float*)alloc((size_t)kB * kRChunks * 128 * 4);
  float* psum2= (float*)alloc((size_t)kB * kRChunks * 128 * 4);
  float* pmax2= (float*)alloc((size_t)kB * kRChunks * 128 * 4);
  ushort* wt1h = (ushort*)alloc((size_t)128 * 256 * 2);
  ushort* wt1l = (ushort*)alloc((size_t)128 * 256 * 2);
  ushort* wt2h = (ushort*)alloc((size_t)128 * 256 * 2);
  ushort* wt2l = (ushort*)alloc((size_t)128 * 256 * 2);
  float* pwn1 = (float*)alloc(128 * 4);
  float* pwn2 = (float*)alloc(128 * 4);

  // ---------------- fused CSR build + prep ----------------
  build_prep<<<129, 1024, 0, stream>>>(src, dst, coff, ccur, ent,
                                       Wl1, Wr1, Wl2, Wr2, pw1, pw2,
                                       wt1h, wt1l, wt2h, wt2l, pwn1, pwn2);

  // ---------------- layer 1 ----------------
  gather1_lds<<<kB * 8, 1024, 0, stream>>>(x, ent, coff, ccur, bufA);
  sage_gemm_mfma<<<kM1 / 256, 1024, 0, stream>>>(bufA, x, nullptr, nullptr,
                                                 wt1h, wt1l, bl1, pwn1, bufB, scr);
  rank_compact<<<kB, 1024, 0, stream>>>(scr, kN, kK1, perm1, gsc1, gsg);
  readout_part<<<kB * kRChunks, 256, 0, stream>>>(bufB, perm1, gsc1, kK1, psum1, pmax1);

  // ---------------- layer 2 (reuses layer-1 CSR; gate staged in gather2 LDS) ----
  gather2_lds<<<kB * 8, 1024, 0, stream>>>(bufB, ent, coff, ccur, perm1, gsg, bufA);
  sage_gemm_mfma<<<kM2 / 256, 1024, 0, stream>>>(bufA, bufB, perm1, gsc1,
                                                 wt2h, wt2l, bl2, pwn2, bufC, scr);
  rank_compact<<<kB, 1024, 0, stream>>>(scr, kK1, kK2, perm2, gsc2, nullptr);
  readout_part<<<kB * kRChunks, 256, 0, stream>>>(bufC, perm2, gsc2, kK2, psum2, pmax2);

  // ---------------- head ----------------
  final_mlp<<<kB, 128, 0, stream>>>(psum1, pmax1, psum2, pmax2,
                                    fW1, fb1, fW2, fb2, (float*)d_out);
}

// Round 9
// 272.726 us; speedup vs baseline: 1.2299x; 1.0828x over previous
//
#include <hip/hip_runtime.h>
#include <cstdint>
#include <cstddef>

namespace {

constexpr int kB    = 64;
constexpr int kN    = 1024;
constexpr int kE    = 655360;
constexpr int kEper = kE / kB;     // 10240
constexpr int kH    = 128;
constexpr int kK1   = 820;
constexpr int kK2   = 656;
constexpr int kM1   = kB * kN;     // 65536
constexpr int kM2   = kB * kK1;    // 52480
constexpr int kM3   = kB * kK2;    // 41984
constexpr int kRChunks = 16;       // readout row-chunks per graph

typedef __attribute__((ext_vector_type(8))) short bf16x8;
typedef __attribute__((ext_vector_type(4))) float f32x4;

__device__ inline ushort f2bf(float f) {            // fp32 -> bf16 RNE bits
  uint u = __float_as_uint(f);
  return (ushort)((u + 0x7fffu + ((u >> 16) & 1u)) >> 16);
}
__device__ inline float bf2f(ushort s) { return __uint_as_float(((uint)s) << 16); }

// packed hi/lo split of 4 floats via v_cvt_pk_bf16_f32 (correctness proven:
// absmax 0 under three different GEMM structures, R6/R7/R8).
__device__ inline void cvt4(const float* f, uint* hh, uint* ll) {
#pragma unroll
  for (int i = 0; i < 2; ++i) {
    uint h;
    asm("v_cvt_pk_bf16_f32 %0, %1, %2" : "=v"(h) : "v"(f[2 * i]), "v"(f[2 * i + 1]));
    const float r0 = __uint_as_float(h << 16);
    const float r1 = __uint_as_float(h & 0xFFFF0000u);
    const float d0 = f[2 * i] - r0;
    const float d1 = f[2 * i + 1] - r1;
    uint l;
    asm("v_cvt_pk_bf16_f32 %0, %1, %2" : "=v"(l) : "v"(d0), "v"(d1));
    hh[i] = h; ll[i] = l;
  }
}

// inclusive block scan over 1024 threads: wave shfl-scan + 16-wavesum scan.
__device__ inline int block_scan_1024(int v, int* wsum /* LDS int[16] */) {
  const int lane = threadIdx.x & 63;
  const int w    = threadIdx.x >> 6;
#pragma unroll
  for (int off = 1; off < 64; off <<= 1) {
    const int n = __shfl_up(v, off);
    if (lane >= off) v += n;
  }
  if (lane == 63) wsum[w] = v;
  __syncthreads();
  if (w == 0) {
    int s = (lane < 16) ? wsum[lane] : 0;
#pragma unroll
    for (int off = 1; off < 16; off <<= 1) {
      const int n = __shfl_up(s, off);
      if (lane >= off) s += n;
    }
    if (lane < 16) wsum[lane] = s;
  }
  __syncthreads();
  if (w > 0) v += wsum[w - 1];
  return v;
}

// ===== fused CSR build + weight prep: one launch, 129 blocks =====
__global__ __launch_bounds__(1024)
void build_prep(const int* __restrict__ src, const int* __restrict__ dst,
                int* __restrict__ coff, int* __restrict__ ccur,
                int* __restrict__ ent,
                const float* __restrict__ Wl1, const float* __restrict__ Wr1,
                const float* __restrict__ Wl2, const float* __restrict__ Wr2,
                const float* __restrict__ pw1, const float* __restrict__ pw2,
                ushort* __restrict__ W1h, ushort* __restrict__ W1l,
                ushort* __restrict__ W2h, ushort* __restrict__ W2l,
                float* __restrict__ pwn1, float* __restrict__ pwn2) {
  const int b   = blockIdx.x;
  const int tid = threadIdx.x;
  if (b >= 128) {                                    // pw normalize
    if (tid >= 256) return;
    const float* pw = (tid < 128) ? pw1 : pw2;
    float* o        = (tid < 128) ? pwn1 : pwn2;
    const int j = tid & 127;
    float sum = 0.0f;
    for (int k = 0; k < 128; ++k) { const float v = pw[k]; sum += v * v; }
    o[j] = pw[j] / sqrtf(sum);
    return;
  }
  if (b >= 64) {                                     // weight split
    const int ob  = (b - 64) * 4 + (tid >> 8);       // old prep block 0..255
    const bool l2 = ob >= 128;
    const int idx = (ob & 127) * 256 + (tid & 255);  // 0..32767
    const int n = idx >> 8, k = idx & 255;
    const float* Wl = l2 ? Wl2 : Wl1;
    const float* Wr = l2 ? Wr2 : Wr1;
    const float w = (k < 128) ? Wl[k * kH + n] : Wr[(k - 128) * kH + n];
    const ushort h = f2bf(w);
    (l2 ? W2h : W1h)[n * 256 + k] = h;
    (l2 ? W2l : W1l)[n * 256 + k] = f2bf(w - bf2f(h));
    return;
  }
  // ---- CSR build for graph b ----
  __shared__ int cnt[1024];
  __shared__ int wsum[16];
  const int g = b;
  const int ebase = g * kEper;
  cnt[tid] = 0;
  __syncthreads();
  for (int e = tid; e < kEper; e += 1024)
    atomicAdd(&cnt[dst[ebase + e] & (kN - 1)], 1);
  __syncthreads();
  const int dg   = cnt[tid];
  const int incl = block_scan_1024(dg, wsum);        // internal barriers
  const int start = ebase + incl - dg;               // exclusive scan
  coff[g * kN + tid] = start;
  ccur[g * kN + tid] = start + dg;                   // end offset
  __syncthreads();
  cnt[tid] = start;                                  // repurpose as cursor
  __syncthreads();
  for (int e = tid; e < kEper; e += 1024) {
    const int d   = dst[ebase + e] & (kN - 1);
    const int pos = atomicAdd(&cnt[d], 1);
    ent[pos] = src[ebase + e] & (kN - 1);
  }
}

// ================= LDS-staged gather-mean (v2) =================
__global__ __launch_bounds__(1024, 8)
void gather1_lds(const float* __restrict__ feat, const int* __restrict__ ent,
                 const int* __restrict__ off, const int* __restrict__ cursor,
                 float* __restrict__ aggout) {
  __shared__ float cache[1024 * 16];                 // 64 KB, stride 16 floats
  const int xcd   = blockIdx.x & 7;
  const int local = blockIdx.x >> 3;
  const int graph = xcd * 8 + (local >> 3);
  const int chunk = local & 7;
  const int tid   = threadIdx.x;
  const int gbase = graph << 10;

#pragma unroll
  for (int ps = 0; ps < 4; ++ps) {
    const int row = ps * 256 + (tid >> 2);
    const int q   = (tid & 3) * 4;
    const float4 v = *(const float4*)(feat + (size_t)(gbase + row) * kH + chunk * 16 + q);
    *(float4*)&cache[row * 16 + q] = v;
  }
  __syncthreads();

  const int grp = tid >> 2;            // group id 0..255 = node within iter
  const int q4  = (tid & 3) * 4;       // this lane's 4 cols inside the chunk

  for (int it = 0; it < 4; ++it) {
    const int lnode = it * 256 + grp;
    const int node  = gbase + lnode;
    const int o0 = off[node];
    const int o1 = cursor[node];
    const int deg = o1 - o0;
    float4 acc = make_float4(0.f, 0.f, 0.f, 0.f);
    int pf[4];
#pragma unroll
    for (int i = 0; i < 4; ++i) pf[i] = (o0 + i < o1) ? ent[o0 + i] : 0;
    for (int eb = 0; eb < deg; eb += 4) {
      int nx[4];
#pragma unroll
      for (int i = 0; i < 4; ++i) {
        const int idx = o0 + eb + 4 + i;
        nx[i] = (idx < o1) ? ent[idx] : 0;
      }
#pragma unroll
      for (int i = 0; i < 4; ++i) {
        const float m = (eb + i < deg) ? 1.0f : 0.0f;   // mask tail
        const float4 v = *(const float4*)&cache[pf[i] * 16 + q4];
        acc.x = fmaf(v.x, m, acc.x);
        acc.y = fmaf(v.y, m, acc.y);
        acc.z = fmaf(v.z, m, acc.z);
        acc.w = fmaf(v.w, m, acc.w);
      }
#pragma unroll
      for (int i = 0; i < 4; ++i) pf[i] = nx[i];
    }
    const float r = 1.0f / fmaxf((float)deg, 1.0f);
    const f32x4 res = {acc.x * r, acc.y * r, acc.z * r, acc.w * r};
    __builtin_nontemporal_store(res, (f32x4*)(aggout + (size_t)node * kH + chunk * 16 + q4));
  }
}

// layer-2 variant (v3): raw ent + per-graph gated-score table gsg in LDS.
__global__ __launch_bounds__(1024, 8)
void gather2_lds(const float* __restrict__ feat, const int* __restrict__ ent,
                 const int* __restrict__ off, const int* __restrict__ cursor,
                 const int* __restrict__ perm, const float* __restrict__ gsg,
                 float* __restrict__ aggout) {
  __shared__ float cache[1024 * 16];                 // 64 KB
  __shared__ float gs[1024];                         // 4 KB gated scores
  const int xcd   = blockIdx.x & 7;
  const int local = blockIdx.x >> 3;
  const int graph = xcd * 8 + (local >> 3);
  const int chunk = local & 7;
  const int tid   = threadIdx.x;
  const int gbase = graph << 10;

#pragma unroll
  for (int ps = 0; ps < 4; ++ps) {
    const int row = ps * 256 + (tid >> 2);
    const int q   = (tid & 3) * 4;
    const float4 v = *(const float4*)(feat + (size_t)(gbase + row) * kH + chunk * 16 + q);
    *(float4*)&cache[row * 16 + q] = v;
  }
  gs[tid] = gsg[gbase + tid];
  __syncthreads();

  const int grp = tid >> 2;
  const int q4  = (tid & 3) * 4;

  for (int it = 0; it < 4; ++it) {
    const int lnode = it * 256 + grp;                // valid < kK1 (820)
    int o0 = 0, o1 = 0;
    if (lnode < kK1) {
      const int orig = perm[graph * kK1 + lnode];
      o0 = off[orig];
      o1 = cursor[orig];
    }
    const int deg = o1 - o0;
    float4 acc = make_float4(0.f, 0.f, 0.f, 0.f);
    int cnt = 0;
    int pf[4];
#pragma unroll
    for (int i = 0; i < 4; ++i) pf[i] = (o0 + i < o1) ? ent[o0 + i] : 0;
    for (int eb = 0; eb < deg; eb += 4) {
      int nx[4];
#pragma unroll
      for (int i = 0; i < 4; ++i) {
        const int idx = o0 + eb + 4 + i;
        nx[i] = (idx < o1) ? ent[idx] : 0;
      }
#pragma unroll
      for (int i = 0; i < 4; ++i) {
        const float raw  = gs[pf[i]];
        const bool  kept = (raw > 0.5f) && (eb + i < deg);
        const float s    = kept ? raw - 2.0f : 0.0f;
        cnt += kept ? 1 : 0;
        const float4 v = *(const float4*)&cache[pf[i] * 16 + q4];
        acc.x = fmaf(v.x, s, acc.x);
        acc.y = fmaf(v.y, s, acc.y);
        acc.z = fmaf(v.z, s, acc.z);
        acc.w = fmaf(v.w, s, acc.w);
      }
#pragma unroll
      for (int i = 0; i < 4; ++i) pf[i] = nx[i];
    }
    const float r = 1.0f / fmaxf((float)cnt, 1.0f);
    const f32x4 res = {acc.x * r, acc.y * r, acc.z * r, acc.w * r};
    if (lnode < kK1)
      __builtin_nontemporal_store(res,
          (f32x4*)(aggout + (size_t)(graph * kK1 + lnode) * kH + chunk * 16 + q4));
  }
}

// ============ split-bf16 MFMA SAGE GEMM + fused score (R19 = R5 revert) ======
// R6/R7/R8 post-mortem: three structural redesigns (W-direct-global, 32-tile
// high-occ, barrier-free streaming) all LOST to this structure (45/70/47 us vs
// ~34). Reverted verbatim to the R5 kernel; sole change: scalar f2bf chain ->
// cvt_pk packed conversion (correctness proven under 3 structures, absmax 0).
// 64-row x 128-col block tile, 4 waves in 2x2, wave tile 32x64 (rt=2, ct=4).
__global__ __launch_bounds__(256)
void sage_gemm_mfma(const float* __restrict__ meanb, const float* __restrict__ xsrc,
                    const int* __restrict__ perm, const float* __restrict__ gsc,
                    const ushort* __restrict__ WTh, const ushort* __restrict__ WTl,
                    const float* __restrict__ bias, const float* __restrict__ pwn,
                    float* __restrict__ outp, float* __restrict__ scr) {
  __shared__ __align__(16) ushort aH[64][32];    // [row][k], 64 B row stride
  __shared__ __align__(16) ushort aL[64][32];
  __shared__ __align__(16) ushort wHs[128][32];  // [n][k] (= W^T)
  __shared__ __align__(16) ushort wLs[128][32];
  __shared__ float sdot[64][2];                  // [row][col-half] score partials
  const int tid  = threadIdx.x;
  const int wid  = tid >> 6;
  const int lane = tid & 63;
  const int quad = lane >> 4;
  const int l16  = lane & 15;
  const int rowbase = blockIdx.x * 64;
  const int wr = (wid >> 1) * 32;                // wave row offset (0/32)
  const int wc = (wid & 1) * 64;                 // wave col offset (0/64)

  f32x4 acc[2][4];
#pragma unroll
  for (int a = 0; a < 2; ++a)
#pragma unroll
    for (int b = 0; b < 4; ++b) acc[a][b] = (f32x4){0.f, 0.f, 0.f, 0.f};

  for (int s = 0; s < 8; ++s) {                  // 8 k-steps of 32 over K=256
    const bool ismean = s < 4;
    const float* sp = ismean ? meanb : xsrc;
    const int kbase = s * 32;
    const int kloc  = ismean ? kbase : kbase - 128;
    // ---- stage A (fp32 -> bf16 hi/lo, cvt_pk packed): 64 rows x 32 k ----
#pragma unroll
    for (int i = 0; i < 2; ++i) {
      const int p   = tid + i * 256;
      const int row = p >> 3;
      const int k4  = (p & 7) * 4;
      const int grow = rowbase + row;
      int srow = grow; float scale = 1.0f;
      if (perm) { if (!ismean) { srow = perm[grow]; scale = gsc[grow]; } }
      const float4 v = *(const float4*)(sp + (size_t)srow * kH + kloc + k4);
      float f[4] = {v.x * scale, v.y * scale, v.z * scale, v.w * scale};
      uint hh[2], ll[2];
      cvt4(f, hh, ll);
      *(uint2*)&aH[row][k4] = make_uint2(hh[0], hh[1]);
      *(uint2*)&aL[row][k4] = make_uint2(ll[0], ll[1]);
    }
    // ---- stage W^T hi/lo: 128 n x 32 k ----
#pragma unroll
    for (int i = 0; i < 4; ++i) {
      const int p  = tid + i * 256;
      const int n  = p >> 3;
      const int k4 = (p & 7) * 4;
      *(ushort4*)&wHs[n][k4] = *(const ushort4*)(WTh + n * 256 + kbase + k4);
      *(ushort4*)&wLs[n][k4] = *(const ushort4*)(WTl + n * 256 + kbase + k4);
    }
    __syncthreads();
    bf16x8 afh[2], afl[2];
#pragma unroll
    for (int rt = 0; rt < 2; ++rt) {
      afh[rt] = *(const bf16x8*)&aH[wr + rt * 16 + l16][quad * 8];
      afl[rt] = *(const bf16x8*)&aL[wr + rt * 16 + l16][quad * 8];
    }
#pragma unroll
    for (int ct = 0; ct < 4; ++ct) {
      const bf16x8 bh = *(const bf16x8*)&wHs[wc + ct * 16 + l16][quad * 8];
      const bf16x8 bl = *(const bf16x8*)&wLs[wc + ct * 16 + l16][quad * 8];
#pragma unroll
      for (int rt = 0; rt < 2; ++rt) {
        acc[rt][ct] = __builtin_amdgcn_mfma_f32_16x16x32_bf16(afh[rt], bh, acc[rt][ct], 0, 0, 0);
        acc[rt][ct] = __builtin_amdgcn_mfma_f32_16x16x32_bf16(afh[rt], bl, acc[rt][ct], 0, 0, 0);
        acc[rt][ct] = __builtin_amdgcn_mfma_f32_16x16x32_bf16(afl[rt], bh, acc[rt][ct], 0, 0, 0);
      }
    }
    __syncthreads();
  }
  // ---- epilogue: bias + relu + store + fused score (64-col partial/wave) ----
  float bv[4], pwv[4];
#pragma unroll
  for (int ct = 0; ct < 4; ++ct) {
    const int col = wc + ct * 16 + l16;
    bv[ct]  = bias[col];
    pwv[ct] = pwn[col];
  }
  float dot[2][4];
#pragma unroll
  for (int rt = 0; rt < 2; ++rt)
#pragma unroll
    for (int reg = 0; reg < 4; ++reg) dot[rt][reg] = 0.0f;
#pragma unroll
  for (int ct = 0; ct < 4; ++ct) {
    const int col = wc + ct * 16 + l16;
#pragma unroll
    for (int rt = 0; rt < 2; ++rt) {
#pragma unroll
      for (int reg = 0; reg < 4; ++reg) {
        const int row = rowbase + wr + rt * 16 + quad * 4 + reg;
        const float o = fmaxf(acc[rt][ct][reg] + bv[ct], 0.0f);
        outp[(size_t)row * kH + col] = o;
        dot[rt][reg] += o * pwv[ct];
      }
    }
  }
#pragma unroll
  for (int rt = 0; rt < 2; ++rt) {
#pragma unroll
    for (int reg = 0; reg < 4; ++reg) {
      float d = dot[rt][reg];
      d += __shfl_xor(d, 1);
      d += __shfl_xor(d, 2);
      d += __shfl_xor(d, 4);
      d += __shfl_xor(d, 8);
      if (l16 == 0) sdot[wr + rt * 16 + quad * 4 + reg][wc >> 6] = d;
    }
  }
  __syncthreads();
  if (tid < 64) scr[rowbase + tid] = tanhf(sdot[tid][0] + sdot[tid][1]);
}

// ================= fused top-K rank + compaction (radix select) =========
__global__ __launch_bounds__(1024)
void rank_compact(const float* __restrict__ scr, int n_per, int K,
                  int* __restrict__ perm, float* __restrict__ gsc,
                  float* __restrict__ gsg) {
  __shared__ int hist[256];
  __shared__ int wsum[16];
  __shared__ uint bT;
  __shared__ int bRem;
  const int g = blockIdx.x, tid = threadIdx.x;
  const float sc = (tid < n_per) ? scr[g * n_per + tid] : -3e30f;  // pad never wins
  const uint bits = __float_as_uint(sc);
  const uint key = (bits & 0x80000000u) ? ~bits : (bits | 0x80000000u);

  uint prefix = 0;
  int rem = K;
#pragma unroll
  for (int shift = 24; shift >= 0; shift -= 8) {
    if (tid < 256) hist[tid] = 0;
    __syncthreads();
    const uint mask = (shift == 24) ? 0u : (0xFFFFFFFFu << (shift + 8));
    if ((key & mask) == prefix)
      atomicAdd(&hist[(key >> shift) & 255], 1);
    __syncthreads();
    if (tid < 64) {
      const int h0 = hist[4 * tid + 0], h1 = hist[4 * tid + 1];
      const int h2 = hist[4 * tid + 2], h3 = hist[4 * tid + 3];
      const int loc = h0 + h1 + h2 + h3;
      int suf = loc;                       // inclusive suffix sum over lanes
#pragma unroll
      for (int d = 1; d < 64; d <<= 1) {
        const int o = __shfl_down(suf, d);
        if (tid + d < 64) suf += o;
      }
      const int above = suf - loc;         // strictly-higher lanes
      int hs[5];
      hs[4] = above;
      hs[3] = above + h3;
      hs[2] = hs[3] + h2;
      hs[1] = hs[2] + h1;
      hs[0] = hs[1] + h0;
#pragma unroll
      for (int q = 0; q < 4; ++q) {
        if (hs[q] >= rem && hs[q + 1] < rem) {   // unique crossing bin
          bT   = prefix | ((uint)(4 * tid + q) << shift);
          bRem = rem - hs[q + 1];
        }
      }
    }
    __syncthreads();
    prefix = bT;
    rem    = bRem;
  }
  const int gt = (key > prefix) ? 1 : 0;
  const int eq = (key == prefix) ? 1 : 0;
  const int incl = block_scan_1024((gt << 11) | eq, wsum);   // internal barriers
  const int excl = incl - ((gt << 11) | eq);
  const int gt_excl = excl >> 11;
  const int eq_excl = excl & 2047;
  const int keep = (tid < n_per) && (gt || (eq && eq_excl < rem));
  if (keep) {
    const int pos = gt_excl + min(eq_excl, rem);
    perm[g * K + pos] = g * n_per + tid;
    gsc[g * K + pos]  = sc;
  }
  if (gsg) gsg[g * kN + tid] = keep ? sc + 2.0f : 0.0f;
}

// ---- readout stage 1: per-(graph, row-chunk) partial mean/max over gated rows ----
__global__ __launch_bounds__(256)
void readout_part(const float* __restrict__ h, const int* __restrict__ perm,
                  const float* __restrict__ gsc, int K,
                  float* __restrict__ psum, float* __restrict__ pmax) {
  const int g     = blockIdx.x >> 4;
  const int chunk = blockIdx.x & (kRChunks - 1);
  const int j     = threadIdx.x & 127;
  const int part  = threadIdx.x >> 7;            // 2 parts
  const int rows  = (K + kRChunks - 1) / kRChunks;
  const int r0 = chunk * rows;
  const int r1 = min(r0 + rows, K);
  float sum = 0.0f, mx = -1e30f;
  for (int r = r0 + part; r < r1; r += 2) {
    const int   row = perm[g * K + r];
    const float sc  = gsc[g * K + r];
    const float v   = h[(size_t)row * kH + j] * sc;
    sum += v;
    mx = fmaxf(mx, v);
  }
  __shared__ float ss[2][128], sm[2][128];
  ss[part][j] = sum;
  sm[part][j] = mx;
  __syncthreads();
  if (part == 0) {
    sum += ss[1][j];
    mx = fmaxf(mx, sm[1][j]);
    psum[(size_t)blockIdx.x * 128 + j] = sum;
    pmax[(size_t)blockIdx.x * 128 + j] = mx;
  }
}

// ---- fused: combine readout chunks (both layers) + 2-layer MLP head ----
__global__ __launch_bounds__(128)
void final_mlp(const float* __restrict__ ps1, const float* __restrict__ pm1,
               const float* __restrict__ ps2, const float* __restrict__ pm2,
               const float* __restrict__ fW1, const float* __restrict__ fb1,
               const float* __restrict__ fW2, const float* __restrict__ fb2,
               float* __restrict__ out) {
  __shared__ float xx[256];
  __shared__ float z[128];
  const int g = blockIdx.x, tid = threadIdx.x;
  float s1 = 0.f, m1 = -1e30f, s2 = 0.f, m2 = -1e30f;
#pragma unroll
  for (int c = 0; c < kRChunks; ++c) {
    s1 += ps1[(size_t)(g * kRChunks + c) * 128 + tid];
    m1 = fmaxf(m1, pm1[(size_t)(g * kRChunks + c) * 128 + tid]);
    s2 += ps2[(size_t)(g * kRChunks + c) * 128 + tid];
    m2 = fmaxf(m2, pm2[(size_t)(g * kRChunks + c) * 128 + tid]);
  }
  xx[tid]       = s1 / (float)kK1 + s2 / (float)kK2;
  xx[tid + 128] = m1 + m2;
  __syncthreads();
  float a = fb1[tid];
  for (int k = 0; k < 256; ++k) a += xx[k] * fW1[k * 128 + tid];
  z[tid] = fmaxf(a, 0.0f);
  __syncthreads();
  if (tid < 10) {
    float o = fb2[tid];
    for (int k = 0; k < 128; ++k) o += z[k] * fW2[k * 10 + tid];
    out[g * 10 + tid] = o;
  }
}

}  // namespace

extern "C" void kernel_launch(void* const* d_in, const int* in_sizes, int n_in,
                              void* d_out, int out_size, void* d_ws, size_t ws_size,
                              hipStream_t stream) {
  const float* x   = (const float*)d_in[0];
  const int*   ei  = (const int*)d_in[1];
  const float* Wl1 = (const float*)d_in[3];
  const float* bl1 = (const float*)d_in[4];
  const float* Wr1 = (const float*)d_in[5];
  const float* Wl2 = (const float*)d_in[6];
  const float* bl2 = (const float*)d_in[7];
  const float* Wr2 = (const float*)d_in[8];
  const float* pw1 = (const float*)d_in[9];
  const float* pw2 = (const float*)d_in[10];
  const float* fW1 = (const float*)d_in[11];
  const float* fb1 = (const float*)d_in[12];
  const float* fW2 = (const float*)d_in[13];
  const float* fb2 = (const float*)d_in[14];
  const int* src = ei;
  const int* dst = ei + kE;
  (void)in_sizes; (void)n_in; (void)out_size; (void)ws_size;

  char* wsb = (char*)d_ws;
  size_t off_b = 0;
  auto alloc = [&](size_t bytes) {
    void* p = wsb + off_b;
    off_b += (bytes + 255) & ~(size_t)255;
    return p;
  };
  float* bufA = (float*)alloc((size_t)kM1 * kH * 4);  // mean1 -> mean2
  float* bufB = (float*)alloc((size_t)kM1 * kH * 4);  // h1
  float* bufC = (float*)alloc((size_t)kM2 * kH * 4);  // h2
  int*   coff = (int*)alloc((size_t)kM1 * 4);
  int*   ccur = (int*)alloc((size_t)kM1 * 4);
  int*   ent  = (int*)alloc((size_t)kE * 4);
  float* scr  = (float*)alloc((size_t)kM1 * 4);
  float* gsg  = (float*)alloc((size_t)kM1 * 4);
  int*   perm1= (int*)alloc((size_t)kM2 * 4);
  float* gsc1 = (float*)alloc((size_t)kM2 * 4);
  int*   perm2= (int*)alloc((size_t)kM3 * 4);
  float* gsc2 = (float*)alloc((size_t)kM3 * 4);
  float* psum1= (float*)alloc((size_t)kB * kRChunks * 128 * 4);
  float* pmax1= (float*)alloc((size_t)kB * kRChunks * 128 * 4);
  float* psum2= (float*)alloc((size_t)kB * kRChunks * 128 * 4);
  float* pmax2= (float*)alloc((size_t)kB * kRChunks * 128 * 4);
  ushort* wt1h = (ushort*)alloc((size_t)128 * 256 * 2);
  ushort* wt1l = (ushort*)alloc((size_t)128 * 256 * 2);
  ushort* wt2h = (ushort*)alloc((size_t)128 * 256 * 2);
  ushort* wt2l = (ushort*)alloc((size_t)128 * 256 * 2);
  float* pwn1 = (float*)alloc(128 * 4);
  float* pwn2 = (float*)alloc(128 * 4);

  // ---------------- fused CSR build + prep ----------------
  build_prep<<<129, 1024, 0, stream>>>(src, dst, coff, ccur, ent,
                                       Wl1, Wr1, Wl2, Wr2, pw1, pw2,
                                       wt1h, wt1l, wt2h, wt2l, pwn1, pwn2);

  // ---------------- layer 1 ----------------
  gather1_lds<<<kB * 8, 1024, 0, stream>>>(x, ent, coff, ccur, bufA);
  sage_gemm_mfma<<<kM1 / 64, 256, 0, stream>>>(bufA, x, nullptr, nullptr,
                                               wt1h, wt1l, bl1, pwn1, bufB, scr);
  rank_compact<<<kB, 1024, 0, stream>>>(scr, kN, kK1, perm1, gsc1, gsg);
  readout_part<<<kB * kRChunks, 256, 0, stream>>>(bufB, perm1, gsc1, kK1, psum1, pmax1);

  // ---------------- layer 2 (reuses layer-1 CSR; gate staged in gather2 LDS) ----
  gather2_lds<<<kB * 8, 1024, 0, stream>>>(bufB, ent, coff, ccur, perm1, gsg, bufA);
  sage_gemm_mfma<<<kM2 / 64, 256, 0, stream>>>(bufA, bufB, perm1, gsc1,
                                               wt2h, wt2l, bl2, pwn2, bufC, scr);
  rank_compact<<<kB, 1024, 0, stream>>>(scr, kK1, kK2, perm2, gsc2, nullptr);
  readout_part<<<kB * kRChunks, 256, 0, stream>>>(bufC, perm2, gsc2, kK2, psum2, pmax2);

  // ---------------- head ----------------
  final_mlp<<<kB, 128, 0, stream>>>(psum1, pmax1, psum2, pmax2,
                                    fW1, fb1, fW2, fb2, (float*)d_out);
}

// Round 10
// 256.790 us; speedup vs baseline: 1.3063x; 1.0621x over previous
//
#include <hip/hip_runtime.h>
#include <cstdint>
#include <cstddef>

namespace {

constexpr int kB    = 64;
constexpr int kN    = 1024;
constexpr int kE    = 655360;
constexpr int kEper = kE / kB;     // 10240
constexpr int kH    = 128;
constexpr int kK1   = 820;
constexpr int kK2   = 656;
constexpr int kM1   = kB * kN;     // 65536
constexpr int kM2   = kB * kK1;    // 52480
constexpr int kM3   = kB * kK2;    // 41984
constexpr int kRChunks = 16;       // readout row-chunks per graph

typedef __attribute__((ext_vector_type(8))) short bf16x8;
typedef __attribute__((ext_vector_type(4))) float f32x4;

__device__ inline ushort f2bf(float f) {            // fp32 -> bf16 RNE bits
  uint u = __float_as_uint(f);
  return (ushort)((u + 0x7fffu + ((u >> 16) & 1u)) >> 16);
}
__device__ inline float bf2f(ushort s) { return __uint_as_float(((uint)s) << 16); }

// packed hi/lo split of 4 floats via v_cvt_pk_bf16_f32 (correctness proven:
// absmax 0 under three different GEMM structures, R6/R7/R8).
__device__ inline void cvt4(const float* f, uint* hh, uint* ll) {
#pragma unroll
  for (int i = 0; i < 2; ++i) {
    uint h;
    asm("v_cvt_pk_bf16_f32 %0, %1, %2" : "=v"(h) : "v"(f[2 * i]), "v"(f[2 * i + 1]));
    const float r0 = __uint_as_float(h << 16);
    const float r1 = __uint_as_float(h & 0xFFFF0000u);
    const float d0 = f[2 * i] - r0;
    const float d1 = f[2 * i + 1] - r1;
    uint l;
    asm("v_cvt_pk_bf16_f32 %0, %1, %2" : "=v"(l) : "v"(d0), "v"(d1));
    hh[i] = h; ll[i] = l;
  }
}

// direct global->LDS copy, 16B/lane (guide §5: compiler never auto-emits;
// LDS dest is wave-uniform base + lane*16, global src is per-lane).
__device__ inline void llds16(const ushort* g, ushort* l) {
  __builtin_amdgcn_global_load_lds(
      (const __attribute__((address_space(1))) void*)g,
      (__attribute__((address_space(3))) void*)l, 16, 0, 0);
}

// inclusive block scan over 1024 threads: wave shfl-scan + 16-wavesum scan.
__device__ inline int block_scan_1024(int v, int* wsum /* LDS int[16] */) {
  const int lane = threadIdx.x & 63;
  const int w    = threadIdx.x >> 6;
#pragma unroll
  for (int off = 1; off < 64; off <<= 1) {
    const int n = __shfl_up(v, off);
    if (lane >= off) v += n;
  }
  if (lane == 63) wsum[w] = v;
  __syncthreads();
  if (w == 0) {
    int s = (lane < 16) ? wsum[lane] : 0;
#pragma unroll
    for (int off = 1; off < 16; off <<= 1) {
      const int n = __shfl_up(s, off);
      if (lane >= off) s += n;
    }
    if (lane < 16) wsum[lane] = s;
  }
  __syncthreads();
  if (w > 0) v += wsum[w - 1];
  return v;
}

// ===== fused CSR build + weight prep: one launch, 129 blocks =====
__global__ __launch_bounds__(1024)
void build_prep(const int* __restrict__ src, const int* __restrict__ dst,
                int* __restrict__ coff, int* __restrict__ ccur,
                int* __restrict__ ent,
                const float* __restrict__ Wl1, const float* __restrict__ Wr1,
                const float* __restrict__ Wl2, const float* __restrict__ Wr2,
                const float* __restrict__ pw1, const float* __restrict__ pw2,
                ushort* __restrict__ W1h, ushort* __restrict__ W1l,
                ushort* __restrict__ W2h, ushort* __restrict__ W2l,
                float* __restrict__ pwn1, float* __restrict__ pwn2) {
  const int b   = blockIdx.x;
  const int tid = threadIdx.x;
  if (b >= 128) {                                    // pw normalize
    if (tid >= 256) return;
    const float* pw = (tid < 128) ? pw1 : pw2;
    float* o        = (tid < 128) ? pwn1 : pwn2;
    const int j = tid & 127;
    float sum = 0.0f;
    for (int k = 0; k < 128; ++k) { const float v = pw[k]; sum += v * v; }
    o[j] = pw[j] / sqrtf(sum);
    return;
  }
  if (b >= 64) {                                     // weight split
    const int ob  = (b - 64) * 4 + (tid >> 8);       // old prep block 0..255
    const bool l2 = ob >= 128;
    const int idx = (ob & 127) * 256 + (tid & 255);  // 0..32767
    const int n = idx >> 8, k = idx & 255;
    const float* Wl = l2 ? Wl2 : Wl1;
    const float* Wr = l2 ? Wr2 : Wr1;
    const float w = (k < 128) ? Wl[k * kH + n] : Wr[(k - 128) * kH + n];
    const ushort h = f2bf(w);
    (l2 ? W2h : W1h)[n * 256 + k] = h;
    (l2 ? W2l : W1l)[n * 256 + k] = f2bf(w - bf2f(h));
    return;
  }
  // ---- CSR build for graph b ----
  __shared__ int cnt[1024];
  __shared__ int wsum[16];
  const int g = b;
  const int ebase = g * kEper;
  cnt[tid] = 0;
  __syncthreads();
  for (int e = tid; e < kEper; e += 1024)
    atomicAdd(&cnt[dst[ebase + e] & (kN - 1)], 1);
  __syncthreads();
  const int dg   = cnt[tid];
  const int incl = block_scan_1024(dg, wsum);        // internal barriers
  const int start = ebase + incl - dg;               // exclusive scan
  coff[g * kN + tid] = start;
  ccur[g * kN + tid] = start + dg;                   // end offset
  __syncthreads();
  cnt[tid] = start;                                  // repurpose as cursor
  __syncthreads();
  for (int e = tid; e < kEper; e += 1024) {
    const int d   = dst[ebase + e] & (kN - 1);
    const int pos = atomicAdd(&cnt[d], 1);
    ent[pos] = src[ebase + e] & (kN - 1);
  }
}

// ================= LDS-staged gather-mean (v2) =================
__global__ __launch_bounds__(1024, 8)
void gather1_lds(const float* __restrict__ feat, const int* __restrict__ ent,
                 const int* __restrict__ off, const int* __restrict__ cursor,
                 float* __restrict__ aggout) {
  __shared__ float cache[1024 * 16];                 // 64 KB, stride 16 floats
  const int xcd   = blockIdx.x & 7;
  const int local = blockIdx.x >> 3;
  const int graph = xcd * 8 + (local >> 3);
  const int chunk = local & 7;
  const int tid   = threadIdx.x;
  const int gbase = graph << 10;

#pragma unroll
  for (int ps = 0; ps < 4; ++ps) {
    const int row = ps * 256 + (tid >> 2);
    const int q   = (tid & 3) * 4;
    const float4 v = *(const float4*)(feat + (size_t)(gbase + row) * kH + chunk * 16 + q);
    *(float4*)&cache[row * 16 + q] = v;
  }
  __syncthreads();

  const int grp = tid >> 2;            // group id 0..255 = node within iter
  const int q4  = (tid & 3) * 4;       // this lane's 4 cols inside the chunk

  for (int it = 0; it < 4; ++it) {
    const int lnode = it * 256 + grp;
    const int node  = gbase + lnode;
    const int o0 = off[node];
    const int o1 = cursor[node];
    const int deg = o1 - o0;
    float4 acc = make_float4(0.f, 0.f, 0.f, 0.f);
    int pf[4];
#pragma unroll
    for (int i = 0; i < 4; ++i) pf[i] = (o0 + i < o1) ? ent[o0 + i] : 0;
    for (int eb = 0; eb < deg; eb += 4) {
      int nx[4];
#pragma unroll
      for (int i = 0; i < 4; ++i) {
        const int idx = o0 + eb + 4 + i;
        nx[i] = (idx < o1) ? ent[idx] : 0;
      }
#pragma unroll
      for (int i = 0; i < 4; ++i) {
        const float m = (eb + i < deg) ? 1.0f : 0.0f;   // mask tail
        const float4 v = *(const float4*)&cache[pf[i] * 16 + q4];
        acc.x = fmaf(v.x, m, acc.x);
        acc.y = fmaf(v.y, m, acc.y);
        acc.z = fmaf(v.z, m, acc.z);
        acc.w = fmaf(v.w, m, acc.w);
      }
#pragma unroll
      for (int i = 0; i < 4; ++i) pf[i] = nx[i];
    }
    const float r = 1.0f / fmaxf((float)deg, 1.0f);
    const f32x4 res = {acc.x * r, acc.y * r, acc.z * r, acc.w * r};
    __builtin_nontemporal_store(res, (f32x4*)(aggout + (size_t)node * kH + chunk * 16 + q4));
  }
}

// layer-2 variant (v3): raw ent + per-graph gated-score table gsg in LDS.
__global__ __launch_bounds__(1024, 8)
void gather2_lds(const float* __restrict__ feat, const int* __restrict__ ent,
                 const int* __restrict__ off, const int* __restrict__ cursor,
                 const int* __restrict__ perm, const float* __restrict__ gsg,
                 float* __restrict__ aggout) {
  __shared__ float cache[1024 * 16];                 // 64 KB
  __shared__ float gs[1024];                         // 4 KB gated scores
  const int xcd   = blockIdx.x & 7;
  const int local = blockIdx.x >> 3;
  const int graph = xcd * 8 + (local >> 3);
  const int chunk = local & 7;
  const int tid   = threadIdx.x;
  const int gbase = graph << 10;

#pragma unroll
  for (int ps = 0; ps < 4; ++ps) {
    const int row = ps * 256 + (tid >> 2);
    const int q   = (tid & 3) * 4;
    const float4 v = *(const float4*)(feat + (size_t)(gbase + row) * kH + chunk * 16 + q);
    *(float4*)&cache[row * 16 + q] = v;
  }
  gs[tid] = gsg[gbase + tid];
  __syncthreads();

  const int grp = tid >> 2;
  const int q4  = (tid & 3) * 4;

  for (int it = 0; it < 4; ++it) {
    const int lnode = it * 256 + grp;                // valid < kK1 (820)
    int o0 = 0, o1 = 0;
    if (lnode < kK1) {
      const int orig = perm[graph * kK1 + lnode];
      o0 = off[orig];
      o1 = cursor[orig];
    }
    const int deg = o1 - o0;
    float4 acc = make_float4(0.f, 0.f, 0.f, 0.f);
    int cnt = 0;
    int pf[4];
#pragma unroll
    for (int i = 0; i < 4; ++i) pf[i] = (o0 + i < o1) ? ent[o0 + i] : 0;
    for (int eb = 0; eb < deg; eb += 4) {
      int nx[4];
#pragma unroll
      for (int i = 0; i < 4; ++i) {
        const int idx = o0 + eb + 4 + i;
        nx[i] = (idx < o1) ? ent[idx] : 0;
      }
#pragma unroll
      for (int i = 0; i < 4; ++i) {
        const float raw  = gs[pf[i]];
        const bool  kept = (raw > 0.5f) && (eb + i < deg);
        const float s    = kept ? raw - 2.0f : 0.0f;
        cnt += kept ? 1 : 0;
        const float4 v = *(const float4*)&cache[pf[i] * 16 + q4];
        acc.x = fmaf(v.x, s, acc.x);
        acc.y = fmaf(v.y, s, acc.y);
        acc.z = fmaf(v.z, s, acc.z);
        acc.w = fmaf(v.w, s, acc.w);
      }
#pragma unroll
      for (int i = 0; i < 4; ++i) pf[i] = nx[i];
    }
    const float r = 1.0f / fmaxf((float)cnt, 1.0f);
    const f32x4 res = {acc.x * r, acc.y * r, acc.z * r, acc.w * r};
    if (lnode < kK1)
      __builtin_nontemporal_store(res,
          (f32x4*)(aggout + (size_t)(graph * kK1 + lnode) * kH + chunk * 16 + q4));
  }
}

// ============ split-bf16 MFMA SAGE GEMM + fused score (R20) ============
// R5 structure (proven best of 4 tried). R20 change: W staging goes through
// __builtin_amdgcn_global_load_lds width=16 (4 direct-to-LDS instrs per wave
// replace 8 loads + 8 stores + addr VALU per thread per k-step; no VGPR
// round-trip). Layout verified: LDS wHs[n][k] is linear, lane l of wave w
// writes base(n0)+l*16 <=> global (n0+(l>>2))*256 + kbase + (l&3)*8.
// Barriers already protect in-flight loads (issue -> barrier1 [vmcnt drain]
// -> ds_read frags -> MFMA -> barrier2 -> next issue).
__global__ __launch_bounds__(256)
void sage_gemm_mfma(const float* __restrict__ meanb, const float* __restrict__ xsrc,
                    const int* __restrict__ perm, const float* __restrict__ gsc,
                    const ushort* __restrict__ WTh, const ushort* __restrict__ WTl,
                    const float* __restrict__ bias, const float* __restrict__ pwn,
                    float* __restrict__ outp, float* __restrict__ scr) {
  __shared__ __align__(16) ushort aH[64][32];    // [row][k], 64 B row stride
  __shared__ __align__(16) ushort aL[64][32];
  __shared__ __align__(16) ushort wHs[128][32];  // [n][k] (= W^T)
  __shared__ __align__(16) ushort wLs[128][32];
  __shared__ float sdot[64][2];                  // [row][col-half] score partials
  const int tid  = threadIdx.x;
  const int wid  = tid >> 6;
  const int lane = tid & 63;
  const int quad = lane >> 4;
  const int l16  = lane & 15;
  const int rowbase = blockIdx.x * 64;
  const int wr = (wid >> 1) * 32;                // wave row offset (0/32)
  const int wc = (wid & 1) * 64;                 // wave col offset (0/64)

  // W-staging geometry: wave w covers rows w*32..w*32+31 as two 16-row
  // global_load_lds bursts; lane l sources row n0+(l>>2), k-chunk (l&3)*8.
  const int n0a = wid * 32;
  const int n0b = wid * 32 + 16;
  const int wrowa = (n0a + (lane >> 2)) * 256 + (lane & 3) * 8;
  const int wrowb = (n0b + (lane >> 2)) * 256 + (lane & 3) * 8;

  f32x4 acc[2][4];
#pragma unroll
  for (int a = 0; a < 2; ++a)
#pragma unroll
    for (int b = 0; b < 4; ++b) acc[a][b] = (f32x4){0.f, 0.f, 0.f, 0.f};

  for (int s = 0; s < 8; ++s) {                  // 8 k-steps of 32 over K=256
    const bool ismean = s < 4;
    const float* sp = ismean ? meanb : xsrc;
    const int kbase = s * 32;
    const int kloc  = ismean ? kbase : kbase - 128;
    // ---- stage A (fp32 -> bf16 hi/lo, cvt_pk packed): 64 rows x 32 k ----
#pragma unroll
    for (int i = 0; i < 2; ++i) {
      const int p   = tid + i * 256;
      const int row = p >> 3;
      const int k4  = (p & 7) * 4;
      const int grow = rowbase + row;
      int srow = grow; float scale = 1.0f;
      if (perm) { if (!ismean) { srow = perm[grow]; scale = gsc[grow]; } }
      const float4 v = *(const float4*)(sp + (size_t)srow * kH + kloc + k4);
      float f[4] = {v.x * scale, v.y * scale, v.z * scale, v.w * scale};
      uint hh[2], ll[2];
      cvt4(f, hh, ll);
      *(uint2*)&aH[row][k4] = make_uint2(hh[0], hh[1]);
      *(uint2*)&aL[row][k4] = make_uint2(ll[0], ll[1]);
    }
    // ---- stage W^T hi/lo direct to LDS (4 instrs per wave) ----
    llds16(WTh + wrowa + kbase, &wHs[n0a][0]);
    llds16(WTh + wrowb + kbase, &wHs[n0b][0]);
    llds16(WTl + wrowa + kbase, &wLs[n0a][0]);
    llds16(WTl + wrowb + kbase, &wLs[n0b][0]);
    __syncthreads();
    bf16x8 afh[2], afl[2];
#pragma unroll
    for (int rt = 0; rt < 2; ++rt) {
      afh[rt] = *(const bf16x8*)&aH[wr + rt * 16 + l16][quad * 8];
      afl[rt] = *(const bf16x8*)&aL[wr + rt * 16 + l16][quad * 8];
    }
#pragma unroll
    for (int ct = 0; ct < 4; ++ct) {
      const bf16x8 bh = *(const bf16x8*)&wHs[wc + ct * 16 + l16][quad * 8];
      const bf16x8 bl = *(const bf16x8*)&wLs[wc + ct * 16 + l16][quad * 8];
#pragma unroll
      for (int rt = 0; rt < 2; ++rt) {
        acc[rt][ct] = __builtin_amdgcn_mfma_f32_16x16x32_bf16(afh[rt], bh, acc[rt][ct], 0, 0, 0);
        acc[rt][ct] = __builtin_amdgcn_mfma_f32_16x16x32_bf16(afh[rt], bl, acc[rt][ct], 0, 0, 0);
        acc[rt][ct] = __builtin_amdgcn_mfma_f32_16x16x32_bf16(afl[rt], bh, acc[rt][ct], 0, 0, 0);
      }
    }
    __syncthreads();
  }
  // ---- epilogue: bias + relu + store + fused score (64-col partial/wave) ----
  float bv[4], pwv[4];
#pragma unroll
  for (int ct = 0; ct < 4; ++ct) {
    const int col = wc + ct * 16 + l16;
    bv[ct]  = bias[col];
    pwv[ct] = pwn[col];
  }
  float dot[2][4];
#pragma unroll
  for (int rt = 0; rt < 2; ++rt)
#pragma unroll
    for (int reg = 0; reg < 4; ++reg) dot[rt][reg] = 0.0f;
#pragma unroll
  for (int ct = 0; ct < 4; ++ct) {
    const int col = wc + ct * 16 + l16;
#pragma unroll
    for (int rt = 0; rt < 2; ++rt) {
#pragma unroll
      for (int reg = 0; reg < 4; ++reg) {
        const int row = rowbase + wr + rt * 16 + quad * 4 + reg;
        const float o = fmaxf(acc[rt][ct][reg] + bv[ct], 0.0f);
        outp[(size_t)row * kH + col] = o;
        dot[rt][reg] += o * pwv[ct];
      }
    }
  }
#pragma unroll
  for (int rt = 0; rt < 2; ++rt) {
#pragma unroll
    for (int reg = 0; reg < 4; ++reg) {
      float d = dot[rt][reg];
      d += __shfl_xor(d, 1);
      d += __shfl_xor(d, 2);
      d += __shfl_xor(d, 4);
      d += __shfl_xor(d, 8);
      if (l16 == 0) sdot[wr + rt * 16 + quad * 4 + reg][wc >> 6] = d;
    }
  }
  __syncthreads();
  if (tid < 64) scr[rowbase + tid] = tanhf(sdot[tid][0] + sdot[tid][1]);
}

// ================= fused top-K rank + compaction (radix select) =========
__global__ __launch_bounds__(1024)
void rank_compact(const float* __restrict__ scr, int n_per, int K,
                  int* __restrict__ perm, float* __restrict__ gsc,
                  float* __restrict__ gsg) {
  __shared__ int hist[256];
  __shared__ int wsum[16];
  __shared__ uint bT;
  __shared__ int bRem;
  const int g = blockIdx.x, tid = threadIdx.x;
  const float sc = (tid < n_per) ? scr[g * n_per + tid] : -3e30f;  // pad never wins
  const uint bits = __float_as_uint(sc);
  const uint key = (bits & 0x80000000u) ? ~bits : (bits | 0x80000000u);

  uint prefix = 0;
  int rem = K;
#pragma unroll
  for (int shift = 24; shift >= 0; shift -= 8) {
    if (tid < 256) hist[tid] = 0;
    __syncthreads();
    const uint mask = (shift == 24) ? 0u : (0xFFFFFFFFu << (shift + 8));
    if ((key & mask) == prefix)
      atomicAdd(&hist[(key >> shift) & 255], 1);
    __syncthreads();
    if (tid < 64) {
      const int h0 = hist[4 * tid + 0], h1 = hist[4 * tid + 1];
      const int h2 = hist[4 * tid + 2], h3 = hist[4 * tid + 3];
      const int loc = h0 + h1 + h2 + h3;
      int suf = loc;                       // inclusive suffix sum over lanes
#pragma unroll
      for (int d = 1; d < 64; d <<= 1) {
        const int o = __shfl_down(suf, d);
        if (tid + d < 64) suf += o;
      }
      const int above = suf - loc;         // strictly-higher lanes
      int hs[5];
      hs[4] = above;
      hs[3] = above + h3;
      hs[2] = hs[3] + h2;
      hs[1] = hs[2] + h1;
      hs[0] = hs[1] + h0;
#pragma unroll
      for (int q = 0; q < 4; ++q) {
        if (hs[q] >= rem && hs[q + 1] < rem) {   // unique crossing bin
          bT   = prefix | ((uint)(4 * tid + q) << shift);
          bRem = rem - hs[q + 1];
        }
      }
    }
    __syncthreads();
    prefix = bT;
    rem    = bRem;
  }
  const int gt = (key > prefix) ? 1 : 0;
  const int eq = (key == prefix) ? 1 : 0;
  const int incl = block_scan_1024((gt << 11) | eq, wsum);   // internal barriers
  const int excl = incl - ((gt << 11) | eq);
  const int gt_excl = excl >> 11;
  const int eq_excl = excl & 2047;
  const int keep = (tid < n_per) && (gt || (eq && eq_excl < rem));
  if (keep) {
    const int pos = gt_excl + min(eq_excl, rem);
    perm[g * K + pos] = g * n_per + tid;
    gsc[g * K + pos]  = sc;
  }
  if (gsg) gsg[g * kN + tid] = keep ? sc + 2.0f : 0.0f;
}

// ---- readout stage 1 (R20): depth-1 prefetch of perm/gsc breaks the
// perm[r] -> h[row] dependent-latency chain ----
__global__ __launch_bounds__(256)
void readout_part(const float* __restrict__ h, const int* __restrict__ perm,
                  const float* __restrict__ gsc, int K,
                  float* __restrict__ psum, float* __restrict__ pmax) {
  const int g     = blockIdx.x >> 4;
  const int chunk = blockIdx.x & (kRChunks - 1);
  const int j     = threadIdx.x & 127;
  const int part  = threadIdx.x >> 7;            // 2 parts
  const int rows  = (K + kRChunks - 1) / kRChunks;
  const int r0 = chunk * rows;
  const int r1 = min(r0 + rows, K);
  float sum = 0.0f, mx = -1e30f;
  int r = r0 + part;
  if (r < r1) {
    int   row = perm[g * K + r];
    float sc  = gsc[g * K + r];
    while (r < r1) {
      const int rn = r + 2;
      int   row_n = 0;
      float sc_n  = 0.0f;
      if (rn < r1) { row_n = perm[g * K + rn]; sc_n = gsc[g * K + rn]; }
      const float v = h[(size_t)row * kH + j] * sc;
      sum += v;
      mx = fmaxf(mx, v);
      row = row_n; sc = sc_n; r = rn;
    }
  }
  __shared__ float ss[2][128], sm[2][128];
  ss[part][j] = sum;
  sm[part][j] = mx;
  __syncthreads();
  if (part == 0) {
    sum += ss[1][j];
    mx = fmaxf(mx, sm[1][j]);
    psum[(size_t)blockIdx.x * 128 + j] = sum;
    pmax[(size_t)blockIdx.x * 128 + j] = mx;
  }
}

// ---- fused: combine readout chunks (both layers) + 2-layer MLP head ----
__global__ __launch_bounds__(128)
void final_mlp(const float* __restrict__ ps1, const float* __restrict__ pm1,
               const float* __restrict__ ps2, const float* __restrict__ pm2,
               const float* __restrict__ fW1, const float* __restrict__ fb1,
               const float* __restrict__ fW2, const float* __restrict__ fb2,
               float* __restrict__ out) {
  __shared__ float xx[256];
  __shared__ float z[128];
  const int g = blockIdx.x, tid = threadIdx.x;
  float s1 = 0.f, m1 = -1e30f, s2 = 0.f, m2 = -1e30f;
#pragma unroll
  for (int c = 0; c < kRChunks; ++c) {
    s1 += ps1[(size_t)(g * kRChunks + c) * 128 + tid];
    m1 = fmaxf(m1, pm1[(size_t)(g * kRChunks + c) * 128 + tid]);
    s2 += ps2[(size_t)(g * kRChunks + c) * 128 + tid];
    m2 = fmaxf(m2, pm2[(size_t)(g * kRChunks + c) * 128 + tid]);
  }
  xx[tid]       = s1 / (float)kK1 + s2 / (float)kK2;
  xx[tid + 128] = m1 + m2;
  __syncthreads();
  float a = fb1[tid];
  for (int k = 0; k < 256; ++k) a += xx[k] * fW1[k * 128 + tid];
  z[tid] = fmaxf(a, 0.0f);
  __syncthreads();
  if (tid < 10) {
    float o = fb2[tid];
    for (int k = 0; k < 128; ++k) o += z[k] * fW2[k * 10 + tid];
    out[g * 10 + tid] = o;
  }
}

}  // namespace

extern "C" void kernel_launch(void* const* d_in, const int* in_sizes, int n_in,
                              void* d_out, int out_size, void* d_ws, size_t ws_size,
                              hipStream_t stream) {
  const float* x   = (const float*)d_in[0];
  const int*   ei  = (const int*)d_in[1];
  const float* Wl1 = (const float*)d_in[3];
  const float* bl1 = (const float*)d_in[4];
  const float* Wr1 = (const float*)d_in[5];
  const float* Wl2 = (const float*)d_in[6];
  const float* bl2 = (const float*)d_in[7];
  const float* Wr2 = (const float*)d_in[8];
  const float* pw1 = (const float*)d_in[9];
  const float* pw2 = (const float*)d_in[10];
  const float* fW1 = (const float*)d_in[11];
  const float* fb1 = (const float*)d_in[12];
  const float* fW2 = (const float*)d_in[13];
  const float* fb2 = (const float*)d_in[14];
  const int* src = ei;
  const int* dst = ei + kE;
  (void)in_sizes; (void)n_in; (void)out_size; (void)ws_size;

  char* wsb = (char*)d_ws;
  size_t off_b = 0;
  auto alloc = [&](size_t bytes) {
    void* p = wsb + off_b;
    off_b += (bytes + 255) & ~(size_t)255;
    return p;
  };
  float* bufA = (float*)alloc((size_t)kM1 * kH * 4);  // mean1 -> mean2
  float* bufB = (float*)alloc((size_t)kM1 * kH * 4);  // h1
  float* bufC = (float*)alloc((size_t)kM2 * kH * 4);  // h2
  int*   coff = (int*)alloc((size_t)kM1 * 4);
  int*   ccur = (int*)alloc((size_t)kM1 * 4);
  int*   ent  = (int*)alloc((size_t)kE * 4);
  float* scr  = (float*)alloc((size_t)kM1 * 4);
  float* gsg  = (float*)alloc((size_t)kM1 * 4);
  int*   perm1= (int*)alloc((size_t)kM2 * 4);
  float* gsc1 = (float*)alloc((size_t)kM2 * 4);
  int*   perm2= (int*)alloc((size_t)kM3 * 4);
  float* gsc2 = (float*)alloc((size_t)kM3 * 4);
  float* psum1= (float*)alloc((size_t)kB * kRChunks * 128 * 4);
  float* pmax1= (float*)alloc((size_t)kB * kRChunks * 128 * 4);
  float* psum2= (float*)alloc((size_t)kB * kRChunks * 128 * 4);
  float* pmax2= (float*)alloc((size_t)kB * kRChunks * 128 * 4);
  ushort* wt1h = (ushort*)alloc((size_t)128 * 256 * 2);
  ushort* wt1l = (ushort*)alloc((size_t)128 * 256 * 2);
  ushort* wt2h = (ushort*)alloc((size_t)128 * 256 * 2);
  ushort* wt2l = (ushort*)alloc((size_t)128 * 256 * 2);
  float* pwn1 = (float*)alloc(128 * 4);
  float* pwn2 = (float*)alloc(128 * 4);

  // ---------------- fused CSR build + prep ----------------
  build_prep<<<129, 1024, 0, stream>>>(src, dst, coff, ccur, ent,
                                       Wl1, Wr1, Wl2, Wr2, pw1, pw2,
                                       wt1h, wt1l, wt2h, wt2l, pwn1, pwn2);

  // ---------------- layer 1 ----------------
  gather1_lds<<<kB * 8, 1024, 0, stream>>>(x, ent, coff, ccur, bufA);
  sage_gemm_mfma<<<kM1 / 64, 256, 0, stream>>>(bufA, x, nullptr, nullptr,
                                               wt1h, wt1l, bl1, pwn1, bufB, scr);
  rank_compact<<<kB, 1024, 0, stream>>>(scr, kN, kK1, perm1, gsc1, gsg);
  readout_part<<<kB * kRChunks, 256, 0, stream>>>(bufB, perm1, gsc1, kK1, psum1, pmax1);

  // ---------------- layer 2 (reuses layer-1 CSR; gate staged in gather2 LDS) ----
  gather2_lds<<<kB * 8, 1024, 0, stream>>>(bufB, ent, coff, ccur, perm1, gsg, bufA);
  sage_gemm_mfma<<<kM2 / 64, 256, 0, stream>>>(bufA, bufB, perm1, gsc1,
                                               wt2h, wt2l, bl2, pwn2, bufC, scr);
  rank_compact<<<kB, 1024, 0, stream>>>(scr, kK1, kK2, perm2, gsc2, nullptr);
  readout_part<<<kB * kRChunks, 256, 0, stream>>>(bufC, perm2, gsc2, kK2, psum2, pmax2);

  // ---------------- head ----------------
  final_mlp<<<kB, 128, 0, stream>>>(psum1, pmax1, psum2, pmax2,
                                    fW1, fb1, fW2, fb2, (float*)d_out);
}

// Round 11
// 250.145 us; speedup vs baseline: 1.3410x; 1.0266x over previous
//
#include <hip/hip_runtime.h>
#include <cstdint>
#include <cstddef>

namespace {

constexpr int kB    = 64;
constexpr int kN    = 1024;
constexpr int kE    = 655360;
constexpr int kEper = kE / kB;     // 10240
constexpr int kH    = 128;
constexpr int kK1   = 820;
constexpr int kK2   = 656;
constexpr int kM1   = kB * kN;     // 65536
constexpr int kM2   = kB * kK1;    // 52480
constexpr int kM3   = kB * kK2;    // 41984
constexpr int kRChunks = 16;       // readout row-chunks per graph (layer 2)

typedef __attribute__((ext_vector_type(8))) short bf16x8;
typedef __attribute__((ext_vector_type(4))) float f32x4;

__device__ inline ushort f2bf(float f) {            // fp32 -> bf16 RNE bits
  uint u = __float_as_uint(f);
  return (ushort)((u + 0x7fffu + ((u >> 16) & 1u)) >> 16);
}
__device__ inline float bf2f(ushort s) { return __uint_as_float(((uint)s) << 16); }

// packed hi/lo split of 4 floats via v_cvt_pk_bf16_f32 (correctness proven:
// absmax 0 under R6/R7/R8/R9/R10).
__device__ inline void cvt4(const float* f, uint* hh, uint* ll) {
#pragma unroll
  for (int i = 0; i < 2; ++i) {
    uint h;
    asm("v_cvt_pk_bf16_f32 %0, %1, %2" : "=v"(h) : "v"(f[2 * i]), "v"(f[2 * i + 1]));
    const float r0 = __uint_as_float(h << 16);
    const float r1 = __uint_as_float(h & 0xFFFF0000u);
    const float d0 = f[2 * i] - r0;
    const float d1 = f[2 * i + 1] - r1;
    uint l;
    asm("v_cvt_pk_bf16_f32 %0, %1, %2" : "=v"(l) : "v"(d0), "v"(d1));
    hh[i] = h; ll[i] = l;
  }
}

// direct global->LDS copy, 16B/lane (R10-proven: -13 us on GEMM W-staging).
// LDS dest must be wave-uniform base (+ lane*16 implicit); global src per-lane.
__device__ inline void llds16(const void* g, void* l) {
  __builtin_amdgcn_global_load_lds(
      (const __attribute__((address_space(1))) void*)g,
      (__attribute__((address_space(3))) void*)l, 16, 0, 0);
}

// inclusive block scan over 1024 threads: wave shfl-scan + 16-wavesum scan.
__device__ inline int block_scan_1024(int v, int* wsum /* LDS int[16] */) {
  const int lane = threadIdx.x & 63;
  const int w    = threadIdx.x >> 6;
#pragma unroll
  for (int off = 1; off < 64; off <<= 1) {
    const int n = __shfl_up(v, off);
    if (lane >= off) v += n;
  }
  if (lane == 63) wsum[w] = v;
  __syncthreads();
  if (w == 0) {
    int s = (lane < 16) ? wsum[lane] : 0;
#pragma unroll
    for (int off = 1; off < 16; off <<= 1) {
      const int n = __shfl_up(s, off);
      if (lane >= off) s += n;
    }
    if (lane < 16) wsum[lane] = s;
  }
  __syncthreads();
  if (w > 0) v += wsum[w - 1];
  return v;
}

// ===== fused CSR build + weight prep: one launch, 129 blocks =====
__global__ __launch_bounds__(1024)
void build_prep(const int* __restrict__ src, const int* __restrict__ dst,
                int* __restrict__ coff, int* __restrict__ ccur,
                int* __restrict__ ent,
                const float* __restrict__ Wl1, const float* __restrict__ Wr1,
                const float* __restrict__ Wl2, const float* __restrict__ Wr2,
                const float* __restrict__ pw1, const float* __restrict__ pw2,
                ushort* __restrict__ W1h, ushort* __restrict__ W1l,
                ushort* __restrict__ W2h, ushort* __restrict__ W2l,
                float* __restrict__ pwn1, float* __restrict__ pwn2) {
  const int b   = blockIdx.x;
  const int tid = threadIdx.x;
  if (b >= 128) {                                    // pw normalize
    if (tid >= 256) return;
    const float* pw = (tid < 128) ? pw1 : pw2;
    float* o        = (tid < 128) ? pwn1 : pwn2;
    const int j = tid & 127;
    float sum = 0.0f;
    for (int k = 0; k < 128; ++k) { const float v = pw[k]; sum += v * v; }
    o[j] = pw[j] / sqrtf(sum);
    return;
  }
  if (b >= 64) {                                     // weight split
    const int ob  = (b - 64) * 4 + (tid >> 8);       // old prep block 0..255
    const bool l2 = ob >= 128;
    const int idx = (ob & 127) * 256 + (tid & 255);  // 0..32767
    const int n = idx >> 8, k = idx & 255;
    const float* Wl = l2 ? Wl2 : Wl1;
    const float* Wr = l2 ? Wr2 : Wr1;
    const float w = (k < 128) ? Wl[k * kH + n] : Wr[(k - 128) * kH + n];
    const ushort h = f2bf(w);
    (l2 ? W2h : W1h)[n * 256 + k] = h;
    (l2 ? W2l : W1l)[n * 256 + k] = f2bf(w - bf2f(h));
    return;
  }
  // ---- CSR build for graph b ----
  __shared__ int cnt[1024];
  __shared__ int wsum[16];
  const int g = b;
  const int ebase = g * kEper;
  cnt[tid] = 0;
  __syncthreads();
  for (int e = tid; e < kEper; e += 1024)
    atomicAdd(&cnt[dst[ebase + e] & (kN - 1)], 1);
  __syncthreads();
  const int dg   = cnt[tid];
  const int incl = block_scan_1024(dg, wsum);        // internal barriers
  const int start = ebase + incl - dg;               // exclusive scan
  coff[g * kN + tid] = start;
  ccur[g * kN + tid] = start + dg;                   // end offset
  __syncthreads();
  cnt[tid] = start;                                  // repurpose as cursor
  __syncthreads();
  for (int e = tid; e < kEper; e += 1024) {
    const int d   = dst[ebase + e] & (kN - 1);
    const int pos = atomicAdd(&cnt[d], 1);
    ent[pos] = src[ebase + e] & (kN - 1);
  }
}

// ================= LDS-staged gather-mean (v2; R21: llds16 staging) ==========
__global__ __launch_bounds__(1024, 8)
void gather1_lds(const float* __restrict__ feat, const int* __restrict__ ent,
                 const int* __restrict__ off, const int* __restrict__ cursor,
                 float* __restrict__ aggout) {
  __shared__ float cache[1024 * 16];                 // 64 KB, stride 16 floats
  const int xcd   = blockIdx.x & 7;
  const int local = blockIdx.x >> 3;
  const int graph = xcd * 8 + (local >> 3);
  const int chunk = local & 7;
  const int tid   = threadIdx.x;
  const int wid   = tid >> 6;
  const int gbase = graph << 10;

  // stage: dest byte = ps*16384 + wid*1024 + lane*16 (wave-uniform base + lane*16)
#pragma unroll
  for (int ps = 0; ps < 4; ++ps) {
    const int row = ps * 256 + (tid >> 2);
    const int q   = (tid & 3) * 4;
    llds16(feat + (size_t)(gbase + row) * kH + chunk * 16 + q,
           cache + ps * 4096 + wid * 256);
  }
  __syncthreads();

  const int grp = tid >> 2;            // group id 0..255 = node within iter
  const int q4  = (tid & 3) * 4;       // this lane's 4 cols inside the chunk

  for (int it = 0; it < 4; ++it) {
    const int lnode = it * 256 + grp;
    const int node  = gbase + lnode;
    const int o0 = off[node];
    const int o1 = cursor[node];
    const int deg = o1 - o0;
    float4 acc = make_float4(0.f, 0.f, 0.f, 0.f);
    int pf[4];
#pragma unroll
    for (int i = 0; i < 4; ++i) pf[i] = (o0 + i < o1) ? ent[o0 + i] : 0;
    for (int eb = 0; eb < deg; eb += 4) {
      int nx[4];
#pragma unroll
      for (int i = 0; i < 4; ++i) {
        const int idx = o0 + eb + 4 + i;
        nx[i] = (idx < o1) ? ent[idx] : 0;
      }
#pragma unroll
      for (int i = 0; i < 4; ++i) {
        const float m = (eb + i < deg) ? 1.0f : 0.0f;   // mask tail
        const float4 v = *(const float4*)&cache[pf[i] * 16 + q4];
        acc.x = fmaf(v.x, m, acc.x);
        acc.y = fmaf(v.y, m, acc.y);
        acc.z = fmaf(v.z, m, acc.z);
        acc.w = fmaf(v.w, m, acc.w);
      }
#pragma unroll
      for (int i = 0; i < 4; ++i) pf[i] = nx[i];
    }
    const float r = 1.0f / fmaxf((float)deg, 1.0f);
    const f32x4 res = {acc.x * r, acc.y * r, acc.z * r, acc.w * r};
    __builtin_nontemporal_store(res, (f32x4*)(aggout + (size_t)node * kH + chunk * 16 + q4));
  }
}

// layer-2 gather (R21): llds16 staging + FUSED layer-1 readout epilogue.
// The block already holds the full h1 slab (cache) and gated scores (gs) in
// LDS — the layer-1 readout for (graph, chunk) is a gated sum/max over those
// rows. Deletes the readout_part layer-1 launch entirely.
__global__ __launch_bounds__(1024, 8)
void gather2_lds(const float* __restrict__ feat, const int* __restrict__ ent,
                 const int* __restrict__ off, const int* __restrict__ cursor,
                 const int* __restrict__ perm, const float* __restrict__ gsg,
                 float* __restrict__ aggout,
                 float* __restrict__ psumg, float* __restrict__ pmaxg) {
  __shared__ float cache[1024 * 16];                 // 64 KB
  __shared__ float gs[1024];                         // 4 KB gated scores
  __shared__ float rps[16][16], rpm[16][16];         // 2 KB readout partials
  const int xcd   = blockIdx.x & 7;
  const int local = blockIdx.x >> 3;
  const int graph = xcd * 8 + (local >> 3);
  const int chunk = local & 7;
  const int tid   = threadIdx.x;
  const int wid   = tid >> 6;
  const int gbase = graph << 10;

#pragma unroll
  for (int ps = 0; ps < 4; ++ps) {
    const int row = ps * 256 + (tid >> 2);
    const int q   = (tid & 3) * 4;
    llds16(feat + (size_t)(gbase + row) * kH + chunk * 16 + q,
           cache + ps * 4096 + wid * 256);
  }
  gs[tid] = gsg[gbase + tid];
  __syncthreads();

  const int grp = tid >> 2;
  const int q4  = (tid & 3) * 4;

  for (int it = 0; it < 4; ++it) {
    const int lnode = it * 256 + grp;                // valid < kK1 (820)
    int o0 = 0, o1 = 0;
    if (lnode < kK1) {
      const int orig = perm[graph * kK1 + lnode];
      o0 = off[orig];
      o1 = cursor[orig];
    }
    const int deg = o1 - o0;
    float4 acc = make_float4(0.f, 0.f, 0.f, 0.f);
    int cnt = 0;
    int pf[4];
#pragma unroll
    for (int i = 0; i < 4; ++i) pf[i] = (o0 + i < o1) ? ent[o0 + i] : 0;
    for (int eb = 0; eb < deg; eb += 4) {
      int nx[4];
#pragma unroll
      for (int i = 0; i < 4; ++i) {
        const int idx = o0 + eb + 4 + i;
        nx[i] = (idx < o1) ? ent[idx] : 0;
      }
#pragma unroll
      for (int i = 0; i < 4; ++i) {
        const float raw  = gs[pf[i]];
        const bool  kept = (raw > 0.5f) && (eb + i < deg);
        const float s    = kept ? raw - 2.0f : 0.0f;
        cnt += kept ? 1 : 0;
        const float4 v = *(const float4*)&cache[pf[i] * 16 + q4];
        acc.x = fmaf(v.x, s, acc.x);
        acc.y = fmaf(v.y, s, acc.y);
        acc.z = fmaf(v.z, s, acc.z);
        acc.w = fmaf(v.w, s, acc.w);
      }
#pragma unroll
      for (int i = 0; i < 4; ++i) pf[i] = nx[i];
    }
    const float r = 1.0f / fmaxf((float)cnt, 1.0f);
    const f32x4 res = {acc.x * r, acc.y * r, acc.z * r, acc.w * r};
    if (lnode < kK1)
      __builtin_nontemporal_store(res,
          (f32x4*)(aggout + (size_t)(graph * kK1 + lnode) * kH + chunk * 16 + q4));
  }

  // ---- fused layer-1 readout: gated sum/max over the LDS-resident slab ----
  __syncthreads();
  const int rcol = tid & 15;
  const int rseg = tid >> 4;                 // 0..63, 16 rows each
  float rs = 0.0f, rm = -1e30f;
#pragma unroll
  for (int i = 0; i < 16; ++i) {
    const int row = rseg * 16 + i;
    const float raw = gs[row];
    if (raw > 0.5f) {
      const float v = cache[row * 16 + rcol] * (raw - 2.0f);
      rs += v;
      rm = fmaxf(rm, v);
    }
  }
  // reduce the 4 segs of each wave that share a col (lane bits 4-5)
  rs += __shfl_xor(rs, 16); rs += __shfl_xor(rs, 32);
  rm = fmaxf(rm, __shfl_xor(rm, 16)); rm = fmaxf(rm, __shfl_xor(rm, 32));
  if ((tid & 48) == 0) { rps[wid][rcol] = rs; rpm[wid][rcol] = rm; }
  __syncthreads();
  if (tid < 16) {
    float ts = 0.0f, tm = -1e30f;
#pragma unroll
    for (int w = 0; w < 16; ++w) { ts += rps[w][tid]; tm = fmaxf(tm, rpm[w][tid]); }
    psumg[graph * kH + chunk * 16 + tid] = ts;
    pmaxg[graph * kH + chunk * 16 + tid] = tm;
  }
}

// ============ split-bf16 MFMA SAGE GEMM + fused score (R21) ============
// R10 structure (best known). R21: perm/gsc row lookups hoisted out of k-loop.
__global__ __launch_bounds__(256)
void sage_gemm_mfma(const float* __restrict__ meanb, const float* __restrict__ xsrc,
                    const int* __restrict__ perm, const float* __restrict__ gsc,
                    const ushort* __restrict__ WTh, const ushort* __restrict__ WTl,
                    const float* __restrict__ bias, const float* __restrict__ pwn,
                    float* __restrict__ outp, float* __restrict__ scr) {
  __shared__ __align__(16) ushort aH[64][32];    // [row][k], 64 B row stride
  __shared__ __align__(16) ushort aL[64][32];
  __shared__ __align__(16) ushort wHs[128][32];  // [n][k] (= W^T)
  __shared__ __align__(16) ushort wLs[128][32];
  __shared__ float sdot[64][2];                  // [row][col-half] score partials
  const int tid  = threadIdx.x;
  const int wid  = tid >> 6;
  const int lane = tid & 63;
  const int quad = lane >> 4;
  const int l16  = lane & 15;
  const int rowbase = blockIdx.x * 64;
  const int wr = (wid >> 1) * 32;                // wave row offset (0/32)
  const int wc = (wid & 1) * 64;                 // wave col offset (0/64)

  // W-staging geometry (R10 global_load_lds path, proven).
  const int n0a = wid * 32;
  const int n0b = wid * 32 + 16;
  const int wrowa = (n0a + (lane >> 2)) * 256 + (lane & 3) * 8;
  const int wrowb = (n0b + (lane >> 2)) * 256 + (lane & 3) * 8;

  // hoisted perm/gsc row info (was re-read every k-step)
  int srow1[2]; float scl1[2];
#pragma unroll
  for (int i = 0; i < 2; ++i) {
    const int grow = rowbase + ((tid + i * 256) >> 3);
    srow1[i] = grow; scl1[i] = 1.0f;
    if (perm) { srow1[i] = perm[grow]; scl1[i] = gsc[grow]; }
  }

  f32x4 acc[2][4];
#pragma unroll
  for (int a = 0; a < 2; ++a)
#pragma unroll
    for (int b = 0; b < 4; ++b) acc[a][b] = (f32x4){0.f, 0.f, 0.f, 0.f};

  for (int s = 0; s < 8; ++s) {                  // 8 k-steps of 32 over K=256
    const bool ismean = s < 4;
    const float* sp = ismean ? meanb : xsrc;
    const int kbase = s * 32;
    const int kloc  = ismean ? kbase : kbase - 128;
    // ---- stage A (fp32 -> bf16 hi/lo, cvt_pk packed): 64 rows x 32 k ----
#pragma unroll
    for (int i = 0; i < 2; ++i) {
      const int p   = tid + i * 256;
      const int row = p >> 3;
      const int k4  = (p & 7) * 4;
      const int srow   = ismean ? (rowbase + row) : srow1[i];
      const float scale = ismean ? 1.0f : scl1[i];
      const float4 v = *(const float4*)(sp + (size_t)srow * kH + kloc + k4);
      float f[4] = {v.x * scale, v.y * scale, v.z * scale, v.w * scale};
      uint hh[2], ll[2];
      cvt4(f, hh, ll);
      *(uint2*)&aH[row][k4] = make_uint2(hh[0], hh[1]);
      *(uint2*)&aL[row][k4] = make_uint2(ll[0], ll[1]);
    }
    // ---- stage W^T hi/lo direct to LDS (4 instrs per wave) ----
    llds16(WTh + wrowa + kbase, &wHs[n0a][0]);
    llds16(WTh + wrowb + kbase, &wHs[n0b][0]);
    llds16(WTl + wrowa + kbase, &wLs[n0a][0]);
    llds16(WTl + wrowb + kbase, &wLs[n0b][0]);
    __syncthreads();
    bf16x8 afh[2], afl[2];
#pragma unroll
    for (int rt = 0; rt < 2; ++rt) {
      afh[rt] = *(const bf16x8*)&aH[wr + rt * 16 + l16][quad * 8];
      afl[rt] = *(const bf16x8*)&aL[wr + rt * 16 + l16][quad * 8];
    }
#pragma unroll
    for (int ct = 0; ct < 4; ++ct) {
      const bf16x8 bh = *(const bf16x8*)&wHs[wc + ct * 16 + l16][quad * 8];
      const bf16x8 bl = *(const bf16x8*)&wLs[wc + ct * 16 + l16][quad * 8];
#pragma unroll
      for (int rt = 0; rt < 2; ++rt) {
        acc[rt][ct] = __builtin_amdgcn_mfma_f32_16x16x32_bf16(afh[rt], bh, acc[rt][ct], 0, 0, 0);
        acc[rt][ct] = __builtin_amdgcn_mfma_f32_16x16x32_bf16(afh[rt], bl, acc[rt][ct], 0, 0, 0);
        acc[rt][ct] = __builtin_amdgcn_mfma_f32_16x16x32_bf16(afl[rt], bh, acc[rt][ct], 0, 0, 0);
      }
    }
    __syncthreads();
  }
  // ---- epilogue: bias + relu + store + fused score (64-col partial/wave) ----
  float bv[4], pwv[4];
#pragma unroll
  for (int ct = 0; ct < 4; ++ct) {
    const int col = wc + ct * 16 + l16;
    bv[ct]  = bias[col];
    pwv[ct] = pwn[col];
  }
  float dot[2][4];
#pragma unroll
  for (int rt = 0; rt < 2; ++rt)
#pragma unroll
    for (int reg = 0; reg < 4; ++reg) dot[rt][reg] = 0.0f;
#pragma unroll
  for (int ct = 0; ct < 4; ++ct) {
    const int col = wc + ct * 16 + l16;
#pragma unroll
    for (int rt = 0; rt < 2; ++rt) {
#pragma unroll
      for (int reg = 0; reg < 4; ++reg) {
        const int row = rowbase + wr + rt * 16 + quad * 4 + reg;
        const float o = fmaxf(acc[rt][ct][reg] + bv[ct], 0.0f);
        outp[(size_t)row * kH + col] = o;
        dot[rt][reg] += o * pwv[ct];
      }
    }
  }
#pragma unroll
  for (int rt = 0; rt < 2; ++rt) {
#pragma unroll
    for (int reg = 0; reg < 4; ++reg) {
      float d = dot[rt][reg];
      d += __shfl_xor(d, 1);
      d += __shfl_xor(d, 2);
      d += __shfl_xor(d, 4);
      d += __shfl_xor(d, 8);
      if (l16 == 0) sdot[wr + rt * 16 + quad * 4 + reg][wc >> 6] = d;
    }
  }
  __syncthreads();
  if (tid < 64) scr[rowbase + tid] = tanhf(sdot[tid][0] + sdot[tid][1]);
}

// ================= fused top-K rank + compaction (radix select) =========
__global__ __launch_bounds__(1024)
void rank_compact(const float* __restrict__ scr, int n_per, int K,
                  int* __restrict__ perm, float* __restrict__ gsc,
                  float* __restrict__ gsg) {
  __shared__ int hist[256];
  __shared__ int wsum[16];
  __shared__ uint bT;
  __shared__ int bRem;
  const int g = blockIdx.x, tid = threadIdx.x;
  const float sc = (tid < n_per) ? scr[g * n_per + tid] : -3e30f;  // pad never wins
  const uint bits = __float_as_uint(sc);
  const uint key = (bits & 0x80000000u) ? ~bits : (bits | 0x80000000u);

  uint prefix = 0;
  int rem = K;
#pragma unroll
  for (int shift = 24; shift >= 0; shift -= 8) {
    if (tid < 256) hist[tid] = 0;
    __syncthreads();
    const uint mask = (shift == 24) ? 0u : (0xFFFFFFFFu << (shift + 8));
    if ((key & mask) == prefix)
      atomicAdd(&hist[(key >> shift) & 255], 1);
    __syncthreads();
    if (tid < 64) {
      const int h0 = hist[4 * tid + 0], h1 = hist[4 * tid + 1];
      const int h2 = hist[4 * tid + 2], h3 = hist[4 * tid + 3];
      const int loc = h0 + h1 + h2 + h3;
      int suf = loc;                       // inclusive suffix sum over lanes
#pragma unroll
      for (int d = 1; d < 64; d <<= 1) {
        const int o = __shfl_down(suf, d);
        if (tid + d < 64) suf += o;
      }
      const int above = suf - loc;         // strictly-higher lanes
      int hs[5];
      hs[4] = above;
      hs[3] = above + h3;
      hs[2] = hs[3] + h2;
      hs[1] = hs[2] + h1;
      hs[0] = hs[1] + h0;
#pragma unroll
      for (int q = 0; q < 4; ++q) {
        if (hs[q] >= rem && hs[q + 1] < rem) {   // unique crossing bin
          bT   = prefix | ((uint)(4 * tid + q) << shift);
          bRem = rem - hs[q + 1];
        }
      }
    }
    __syncthreads();
    prefix = bT;
    rem    = bRem;
  }
  const int gt = (key > prefix) ? 1 : 0;
  const int eq = (key == prefix) ? 1 : 0;
  const int incl = block_scan_1024((gt << 11) | eq, wsum);   // internal barriers
  const int excl = incl - ((gt << 11) | eq);
  const int gt_excl = excl >> 11;
  const int eq_excl = excl & 2047;
  const int keep = (tid < n_per) && (gt || (eq && eq_excl < rem));
  if (keep) {
    const int pos = gt_excl + min(eq_excl, rem);
    perm[g * K + pos] = g * n_per + tid;
    gsc[g * K + pos]  = sc;
  }
  if (gsg) gsg[g * kN + tid] = keep ? sc + 2.0f : 0.0f;
}

// ---- readout stage 1 (layer 2 only now): depth-1 prefetch of perm/gsc ----
__global__ __launch_bounds__(256)
void readout_part(const float* __restrict__ h, const int* __restrict__ perm,
                  const float* __restrict__ gsc, int K,
                  float* __restrict__ psum, float* __restrict__ pmax) {
  const int g     = blockIdx.x >> 4;
  const int chunk = blockIdx.x & (kRChunks - 1);
  const int j     = threadIdx.x & 127;
  const int part  = threadIdx.x >> 7;            // 2 parts
  const int rows  = (K + kRChunks - 1) / kRChunks;
  const int r0 = chunk * rows;
  const int r1 = min(r0 + rows, K);
  float sum = 0.0f, mx = -1e30f;
  int r = r0 + part;
  if (r < r1) {
    int   row = perm[g * K + r];
    float sc  = gsc[g * K + r];
    while (r < r1) {
      const int rn = r + 2;
      int   row_n = 0;
      float sc_n  = 0.0f;
      if (rn < r1) { row_n = perm[g * K + rn]; sc_n = gsc[g * K + rn]; }
      const float v = h[(size_t)row * kH + j] * sc;
      sum += v;
      mx = fmaxf(mx, v);
      row = row_n; sc = sc_n; r = rn;
    }
  }
  __shared__ float ss[2][128], sm[2][128];
  ss[part][j] = sum;
  sm[part][j] = mx;
  __syncthreads();
  if (part == 0) {
    sum += ss[1][j];
    mx = fmaxf(mx, sm[1][j]);
    psum[(size_t)blockIdx.x * 128 + j] = sum;
    pmax[(size_t)blockIdx.x * 128 + j] = mx;
  }
}

// ---- fused: combine readouts (L1 pre-reduced; L2 chunked) + 2-layer MLP head ----
__global__ __launch_bounds__(128)
void final_mlp(const float* __restrict__ ps1, const float* __restrict__ pm1,
               const float* __restrict__ ps2, const float* __restrict__ pm2,
               const float* __restrict__ fW1, const float* __restrict__ fb1,
               const float* __restrict__ fW2, const float* __restrict__ fb2,
               float* __restrict__ out) {
  __shared__ float xx[256];
  __shared__ float z[128];
  const int g = blockIdx.x, tid = threadIdx.x;
  const float s1 = ps1[(size_t)g * 128 + tid];     // fully reduced in gather2
  const float m1 = pm1[(size_t)g * 128 + tid];
  float s2 = 0.f, m2 = -1e30f;
#pragma unroll
  for (int c = 0; c < kRChunks; ++c) {
    s2 += ps2[(size_t)(g * kRChunks + c) * 128 + tid];
    m2 = fmaxf(m2, pm2[(size_t)(g * kRChunks + c) * 128 + tid]);
  }
  xx[tid]       = s1 / (float)kK1 + s2 / (float)kK2;
  xx[tid + 128] = m1 + m2;
  __syncthreads();
  float a = fb1[tid];
  for (int k = 0; k < 256; ++k) a += xx[k] * fW1[k * 128 + tid];
  z[tid] = fmaxf(a, 0.0f);
  __syncthreads();
  if (tid < 10) {
    float o = fb2[tid];
    for (int k = 0; k < 128; ++k) o += z[k] * fW2[k * 10 + tid];
    out[g * 10 + tid] = o;
  }
}

}  // namespace

extern "C" void kernel_launch(void* const* d_in, const int* in_sizes, int n_in,
                              void* d_out, int out_size, void* d_ws, size_t ws_size,
                              hipStream_t stream) {
  const float* x   = (const float*)d_in[0];
  const int*   ei  = (const int*)d_in[1];
  const float* Wl1 = (const float*)d_in[3];
  const float* bl1 = (const float*)d_in[4];
  const float* Wr1 = (const float*)d_in[5];
  const float* Wl2 = (const float*)d_in[6];
  const float* bl2 = (const float*)d_in[7];
  const float* Wr2 = (const float*)d_in[8];
  const float* pw1 = (const float*)d_in[9];
  const float* pw2 = (const float*)d_in[10];
  const float* fW1 = (const float*)d_in[11];
  const float* fb1 = (const float*)d_in[12];
  const float* fW2 = (const float*)d_in[13];
  const float* fb2 = (const float*)d_in[14];
  const int* src = ei;
  const int* dst = ei + kE;
  (void)in_sizes; (void)n_in; (void)out_size; (void)ws_size;

  char* wsb = (char*)d_ws;
  size_t off_b = 0;
  auto alloc = [&](size_t bytes) {
    void* p = wsb + off_b;
    off_b += (bytes + 255) & ~(size_t)255;
    return p;
  };
  float* bufA = (float*)alloc((size_t)kM1 * kH * 4);  // mean1 -> mean2
  float* bufB = (float*)alloc((size_t)kM1 * kH * 4);  // h1
  float* bufC = (float*)alloc((size_t)kM2 * kH * 4);  // h2
  int*   coff = (int*)alloc((size_t)kM1 * 4);
  int*   ccur = (int*)alloc((size_t)kM1 * 4);
  int*   ent  = (int*)alloc((size_t)kE * 4);
  float* scr  = (float*)alloc((size_t)kM1 * 4);
  float* gsg  = (float*)alloc((size_t)kM1 * 4);
  int*   perm1= (int*)alloc((size_t)kM2 * 4);
  float* gsc1 = (float*)alloc((size_t)kM2 * 4);
  int*   perm2= (int*)alloc((size_t)kM3 * 4);
  float* gsc2 = (float*)alloc((size_t)kM3 * 4);
  float* psum1= (float*)alloc((size_t)kB * 128 * 4);        // L1: fully reduced
  float* pmax1= (float*)alloc((size_t)kB * 128 * 4);
  float* psum2= (float*)alloc((size_t)kB * kRChunks * 128 * 4);
  float* pmax2= (float*)alloc((size_t)kB * kRChunks * 128 * 4);
  ushort* wt1h = (ushort*)alloc((size_t)128 * 256 * 2);
  ushort* wt1l = (ushort*)alloc((size_t)128 * 256 * 2);
  ushort* wt2h = (ushort*)alloc((size_t)128 * 256 * 2);
  ushort* wt2l = (ushort*)alloc((size_t)128 * 256 * 2);
  float* pwn1 = (float*)alloc(128 * 4);
  float* pwn2 = (float*)alloc(128 * 4);

  // ---------------- fused CSR build + prep ----------------
  build_prep<<<129, 1024, 0, stream>>>(src, dst, coff, ccur, ent,
                                       Wl1, Wr1, Wl2, Wr2, pw1, pw2,
                                       wt1h, wt1l, wt2h, wt2l, pwn1, pwn2);

  // ---------------- layer 1 ----------------
  gather1_lds<<<kB * 8, 1024, 0, stream>>>(x, ent, coff, ccur, bufA);
  sage_gemm_mfma<<<kM1 / 64, 256, 0, stream>>>(bufA, x, nullptr, nullptr,
                                               wt1h, wt1l, bl1, pwn1, bufB, scr);
  rank_compact<<<kB, 1024, 0, stream>>>(scr, kN, kK1, perm1, gsc1, gsg);

  // ---------------- layer 2 (gather2 also emits the layer-1 readout) --------
  gather2_lds<<<kB * 8, 1024, 0, stream>>>(bufB, ent, coff, ccur, perm1, gsg,
                                           bufA, psum1, pmax1);
  sage_gemm_mfma<<<kM2 / 64, 256, 0, stream>>>(bufA, bufB, perm1, gsc1,
                                               wt2h, wt2l, bl2, pwn2, bufC, scr);
  rank_compact<<<kB, 1024, 0, stream>>>(scr, kK1, kK2, perm2, gsc2, nullptr);
  readout_part<<<kB * kRChunks, 256, 0, stream>>>(bufC, perm2, gsc2, kK2, psum2, pmax2);

  // ---------------- head ----------------
  final_mlp<<<kB, 128, 0, stream>>>(psum1, pmax1, psum2, pmax2,
                                    fW1, fb1, fW2, fb2, (float*)d_out);
}